// Round 3
// baseline (1694.080 us; speedup 1.0000x reference)
//
#include <hip/hip_runtime.h>
#include <hip/hip_bf16.h>

#define N_NODES 50000
#define N_EDGES 800000

// ---------- dual-dtype load/store ----------
__device__ __forceinline__ float loadF(const void* p, size_t i, bool isbf) {
    return isbf ? __bfloat162float(((const __hip_bfloat16*)p)[i]) : ((const float*)p)[i];
}
__device__ __forceinline__ void storeT(__hip_bfloat16* p, size_t i, float v) { p[i] = __float2bfloat16(v); }
__device__ __forceinline__ void storeT(float* p, size_t i, float v) { p[i] = v; }

// ---------- dtype detect: even-index uint16 words of x ----------
// bf16 array of N(0,1): even words are bf16 values, exponent in [117,134] ~99%.
// fp32 array: even words are mantissa low halves, ~7% land in that range.
__global__ void detect_k(const unsigned short* __restrict__ xw, int* __restrict__ flag) {
    int t = threadIdx.x;  // 64 threads
    int cnt = 0;
    for (int i = t; i < 512; i += 64) {
        unsigned e = (xw[2 * i] >> 7) & 0xFFu;
        if (e >= 117u && e <= 134u) cnt++;
    }
    for (int off = 32; off; off >>= 1) cnt += __shfl_down(cnt, off, 64);
    if (t == 0) *flag = (cnt >= 256) ? 1 : 0;   // 1 = inputs are bf16
}

// ---------- CSR build ----------
__global__ void hist_k(const int* __restrict__ dst, int* __restrict__ cnt, int E) {
    int e = blockIdx.x * blockDim.x + threadIdx.x;
    if (e < E) atomicAdd(&cnt[dst[e]], 1);
}

__global__ void scan1_k(const int* __restrict__ deg, int* __restrict__ rowptr,
                        int* __restrict__ bsum, int N) {
    __shared__ int s[256];
    int t = threadIdx.x, g = blockIdx.x * 256 + t;
    int v = (g < N) ? deg[g] : 0;
    s[t] = v; __syncthreads();
    for (int off = 1; off < 256; off <<= 1) {
        int x = (t >= off) ? s[t - off] : 0;
        __syncthreads();
        s[t] += x;
        __syncthreads();
    }
    if (g < N) rowptr[g] = s[t] - v;          // block-local exclusive
    if (t == 255) bsum[blockIdx.x] = s[255];  // block total
}

__global__ void scan2_k(int* __restrict__ bsum, int nb) {
    __shared__ int s[256];
    int t = threadIdx.x;
    int v = (t < nb) ? bsum[t] : 0;
    s[t] = v; __syncthreads();
    for (int off = 1; off < 256; off <<= 1) {
        int x = (t >= off) ? s[t - off] : 0;
        __syncthreads();
        s[t] += x;
        __syncthreads();
    }
    if (t < nb) bsum[t] = s[t] - v;           // exclusive block offsets
}

__global__ void scan3_k(int* __restrict__ rowptr, const int* __restrict__ bsum, int N, int E) {
    int g = blockIdx.x * 256 + threadIdx.x;
    if (g < N) rowptr[g] += bsum[blockIdx.x];
    if (g == 0) rowptr[N] = E;
}

// consumes cursor (holds deg after hist); stores SRC node id per CSR slot
__global__ void scatter_k(const int* __restrict__ src, const int* __restrict__ dst,
                          const int* __restrict__ rowptr, int* __restrict__ cursor,
                          int* __restrict__ ecol, int E) {
    int e = blockIdx.x * blockDim.x + threadIdx.x;
    if (e >= E) return;
    int d = dst[e];
    int r = atomicSub(&cursor[d], 1);          // old value
    ecol[rowptr[d] + r - 1] = src[e];
}

// ---------- per-row GEMM: out[n,c] = sum_k X[n,k] W[k,c], bf16 out ----------
__global__ void gemm_k(const void* __restrict__ X, int x_internal,
                       const void* __restrict__ W, const int* __restrict__ flag,
                       __hip_bfloat16* __restrict__ out, int K, int M) {
    extern __shared__ float xs[];
    bool extbf = (*flag != 0);
    bool xbf = x_internal ? true : extbf;
    int n = blockIdx.x;
    for (int k = threadIdx.x; k < K; k += blockDim.x) xs[k] = loadF(X, (size_t)n * K + k, xbf);
    __syncthreads();
    int c = threadIdx.x;
    if (c < M) {
        float acc = 0.f;
        for (int k = 0; k < K; ++k) acc += xs[k] * loadF(W, (size_t)k * M + c, extbf);
        out[(size_t)n * M + c] = __float2bfloat16(acc);
    }
}

// ---------- attention coefficients ----------
__global__ void attn_k(const __hip_bfloat16* __restrict__ Hp, const void* __restrict__ al,
                       const void* __restrict__ ar, const int* __restrict__ flag,
                       float* __restrict__ el, float* __restrict__ er, int H, int F) {
    __shared__ float vl[256];
    __shared__ float vr[256];
    bool bf = (*flag != 0);
    int n = blockIdx.x, t = threadIdx.x;
    int HF = H * F;
    if (t < HF) {
        float v = __bfloat162float(Hp[(size_t)n * HF + t]);
        vl[t] = v * loadF(al, t, bf);
        vr[t] = v * loadF(ar, t, bf);
    }
    __syncthreads();
    if (t < H) {
        float sl = 0.f, sr = 0.f;
        int b = t * F;
        for (int f = 0; f < F; ++f) { sl += vl[b + f]; sr += vr[b + f]; }
        el[n * H + t] = sl;
        er[n * H + t] = sr;
    }
}

// ---------- CSR softmax-aggregation: one block per dst node ----------
template <int H, int F, int BLOCK, bool DOELU, typename TOUT>
__global__ void aggr_k(const int* __restrict__ rowptr, const int* __restrict__ ecol,
                       const float* __restrict__ el, const float* __restrict__ er,
                       const __hip_bfloat16* __restrict__ Hp, TOUT* __restrict__ out) {
    constexpr int HF = H * F;
    constexpr int G = BLOCK / H;   // lanes per head group (32 or 64; pow2)
    constexpr int CAP = 64;        // edge tile
    __shared__ float s_m[H];
    __shared__ float s_s[H];
    __shared__ int s_src[CAP];
    __shared__ float s_a[CAP][H];
    int n = blockIdx.x, t = threadIdx.x;
    int beg = rowptr[n];
    int deg = rowptr[n + 1] - beg;

    // phase A: per-head max, then sum of exp
    int h = t / G, l = t % G;
    float er_h = er[n * H + h];
    float m = -1e30f;
    for (int i = l; i < deg; i += G) {
        int s = ecol[beg + i];
        float v = el[s * H + h] + er_h;
        v = (v >= 0.f) ? v : 0.2f * v;
        m = fmaxf(m, v);
    }
    for (int off = G / 2; off; off >>= 1) m = fmaxf(m, __shfl_down(m, off, G));
    m = __shfl(m, 0, G);
    float ssum = 0.f;
    for (int i = l; i < deg; i += G) {
        int s = ecol[beg + i];
        float v = el[s * H + h] + er_h;
        v = (v >= 0.f) ? v : 0.2f * v;
        ssum += expf(v - m);
    }
    for (int off = G / 2; off; off >>= 1) ssum += __shfl_down(ssum, off, G);
    if (l == 0) { s_m[h] = m; s_s[h] = ssum; }
    __syncthreads();

    // phase B: tiled alpha + feature accumulation
    float acc = 0.f;
    for (int base = 0; base < deg; base += CAP) {
        int cnt = min(CAP, deg - base);
        for (int idx = t; idx < cnt * H; idx += BLOCK) {
            int i = idx / H, h2 = idx % H;
            int s = ecol[beg + base + i];
            if (h2 == 0) s_src[i] = s;
            float v = el[s * H + h2] + er[n * H + h2];
            v = (v >= 0.f) ? v : 0.2f * v;
            s_a[i][h2] = expf(v - s_m[h2]) / (s_s[h2] + 1e-16f);
        }
        __syncthreads();
        if (t < HF) {
            int hh = t / F;
            for (int i = 0; i < cnt; ++i)
                acc += s_a[i][hh] * __bfloat162float(Hp[(size_t)s_src[i] * HF + t]);
        }
        __syncthreads();
    }
    if (t < HF) {
        float r = DOELU ? ((acc > 0.f) ? acc : expm1f(acc)) : acc;
        storeT(out, (size_t)n * HF + t, r);
    }
}

// ---------- log_softmax, dual-dtype output ----------
__global__ void logsm_k(const float* __restrict__ acc, void* __restrict__ outp,
                        const int* __restrict__ flag) {
    __shared__ float vals[40];
    __shared__ float lse;
    int n = blockIdx.x, t = threadIdx.x;
    if (t < 40) vals[t] = acc[(size_t)n * 40 + t];
    __syncthreads();
    if (t == 0) {
        float m = vals[0];
        for (int i = 1; i < 40; ++i) m = fmaxf(m, vals[i]);
        float s = 0.f;
        for (int i = 0; i < 40; ++i) s += expf(vals[i] - m);
        lse = m + logf(s);
    }
    __syncthreads();
    if (t < 40) {
        float r = vals[t] - lse;
        if (*flag) ((__hip_bfloat16*)outp)[(size_t)n * 40 + t] = __float2bfloat16(r);
        else       ((float*)outp)[(size_t)n * 40 + t] = r;
    }
}

extern "C" void kernel_launch(void* const* d_in, const int* in_sizes, int n_in,
                              void* d_out, int out_size, void* d_ws, size_t ws_size,
                              hipStream_t stream) {
    const int N = N_NODES, E = N_EDGES;
    const void* x   = d_in[0];
    const int* src  = (const int*)d_in[1];
    const int* dst  = (const int*)d_in[2];
    const void* W1  = d_in[3];
    const void* al1 = d_in[4];
    const void* ar1 = d_in[5];
    const void* W2  = d_in[6];
    const void* al2 = d_in[7];
    const void* ar2 = d_in[8];
    const void* Wo  = d_in[9];
    const void* alo = d_in[10];
    const void* aro = d_in[11];

    // workspace layout (~57.8 MB), 256-B aligned chunks
    char* w = (char*)d_ws;
    auto alloc = [&](size_t bytes) { void* p = (void*)w; w += (bytes + 255) & ~(size_t)255; return p; };
    int* flag      = (int*)alloc(4);
    int* rowptr    = (int*)alloc((size_t)(N + 1) * 4);
    int* cursor    = (int*)alloc((size_t)N * 4);
    int* bsum      = (int*)alloc(256 * 4);
    int* ecol      = (int*)alloc((size_t)E * 4);
    float* el      = (float*)alloc((size_t)N * 8 * 4);
    float* er      = (float*)alloc((size_t)N * 8 * 4);
    __hip_bfloat16* Hp   = (__hip_bfloat16*)alloc((size_t)N * 256 * 2);
    __hip_bfloat16* Hagg = (__hip_bfloat16*)alloc((size_t)N * 256 * 2);
    float* Fout = (float*)Hagg;  // alias: Hagg dead when Fout is written (output layer)

    int EB = (E + 255) / 256;
    int NB = (N + 255) / 256;

    // dtype flag + CSR (shared by all 3 layers)
    detect_k<<<1, 64, 0, stream>>>((const unsigned short*)x, flag);
    hipMemsetAsync(cursor, 0, (size_t)N * 4, stream);
    hist_k<<<EB, 256, 0, stream>>>(dst, cursor, E);
    scan1_k<<<NB, 256, 0, stream>>>(cursor, rowptr, bsum, N);
    scan2_k<<<1, 256, 0, stream>>>(bsum, NB);
    scan3_k<<<NB, 256, 0, stream>>>(rowptr, bsum, N, E);
    scatter_k<<<EB, 256, 0, stream>>>(src, dst, rowptr, cursor, ecol, E);

    // ---- layer 1: x[N,128] @ W1 -> [N,8,32], GAT, ELU ----
    gemm_k<<<N, 256, 128 * 4, stream>>>(x, 0, W1, flag, Hp, 128, 256);
    attn_k<<<N, 256, 0, stream>>>(Hp, al1, ar1, flag, el, er, 8, 32);
    aggr_k<8, 32, 256, true, __hip_bfloat16><<<N, 256, 0, stream>>>(rowptr, ecol, el, er, Hp, Hagg);

    // ---- layer 2: Hagg[N,256] @ W2 -> [N,8,32], GAT, ELU ----
    gemm_k<<<N, 256, 256 * 4, stream>>>(Hagg, 1, W2, flag, Hp, 256, 256);
    attn_k<<<N, 256, 0, stream>>>(Hp, al2, ar2, flag, el, er, 8, 32);
    aggr_k<8, 32, 256, true, __hip_bfloat16><<<N, 256, 0, stream>>>(rowptr, ecol, el, er, Hp, Hagg);

    // ---- output layer: Hagg[N,256] @ Wo -> [N,40], GAT(1 head), log_softmax ----
    gemm_k<<<N, 64, 256 * 4, stream>>>(Hagg, 1, Wo, flag, Hp, 256, 40);
    attn_k<<<N, 64, 0, stream>>>(Hp, alo, aro, flag, el, er, 1, 40);
    aggr_k<1, 40, 64, false, float><<<N, 64, 0, stream>>>(rowptr, ecol, el, er, Hp, Fout);
    logsm_k<<<N, 64, 0, stream>>>(Fout, d_out, flag);
}

// Round 4
// 801.949 us; speedup vs baseline: 2.1125x; 2.1125x over previous
//
#include <hip/hip_runtime.h>
#include <hip/hip_bf16.h>

#define N_NODES 50000
#define N_EDGES 800000

typedef __bf16 bf16x8 __attribute__((ext_vector_type(8)));
typedef float f32x4 __attribute__((ext_vector_type(4)));

// ---------- dual-dtype load ----------
__device__ __forceinline__ float loadF(const void* p, size_t i, bool isbf) {
    return isbf ? __bfloat162float(((const __hip_bfloat16*)p)[i]) : ((const float*)p)[i];
}
__device__ __forceinline__ void storeT(__hip_bfloat16* p, size_t i, float v) { p[i] = __float2bfloat16(v); }
__device__ __forceinline__ void storeT(float* p, size_t i, float v) { p[i] = v; }

// ---------- dtype detect: even-index uint16 words of x ----------
__global__ void detect_k(const unsigned short* __restrict__ xw, int* __restrict__ flag) {
    int t = threadIdx.x;  // 64 threads
    int cnt = 0;
    for (int i = t; i < 512; i += 64) {
        unsigned e = (xw[2 * i] >> 7) & 0xFFu;
        if (e >= 117u && e <= 134u) cnt++;
    }
    for (int off = 32; off; off >>= 1) cnt += __shfl_down(cnt, off, 64);
    if (t == 0) *flag = (cnt >= 256) ? 1 : 0;   // 1 = inputs are bf16
}

// ---------- convert n8*8 elements to bf16 (copy if already bf16) ----------
__global__ void cvt8_k(const void* __restrict__ in, unsigned short* __restrict__ out,
                       int n8, const int* __restrict__ flag) {
    int i = blockIdx.x * blockDim.x + threadIdx.x;
    if (i >= n8) return;
    if (*flag) {
        ((uint4*)out)[i] = ((const uint4*)in)[i];
    } else {
        const float* f = (const float*)in + (size_t)i * 8;
        unsigned short r[8];
        for (int j = 0; j < 8; ++j) {
            __hip_bfloat16 h = __float2bfloat16(f[j]);
            r[j] = *(unsigned short*)&h;
        }
        *(uint4*)(out + (size_t)i * 8) = *(uint4*)r;
    }
}

// ---------- CSR build ----------
__global__ void hist_k(const int* __restrict__ dst, int* __restrict__ cnt, int E) {
    int e = blockIdx.x * blockDim.x + threadIdx.x;
    if (e < E) atomicAdd(&cnt[dst[e]], 1);
}

__global__ void scan1_k(const int* __restrict__ deg, int* __restrict__ rowptr,
                        int* __restrict__ bsum, int N) {
    __shared__ int s[256];
    int t = threadIdx.x, g = blockIdx.x * 256 + t;
    int v = (g < N) ? deg[g] : 0;
    s[t] = v; __syncthreads();
    for (int off = 1; off < 256; off <<= 1) {
        int x = (t >= off) ? s[t - off] : 0;
        __syncthreads();
        s[t] += x;
        __syncthreads();
    }
    if (g < N) rowptr[g] = s[t] - v;
    if (t == 255) bsum[blockIdx.x] = s[255];
}

__global__ void scan2_k(int* __restrict__ bsum, int nb) {
    __shared__ int s[256];
    int t = threadIdx.x;
    int v = (t < nb) ? bsum[t] : 0;
    s[t] = v; __syncthreads();
    for (int off = 1; off < 256; off <<= 1) {
        int x = (t >= off) ? s[t - off] : 0;
        __syncthreads();
        s[t] += x;
        __syncthreads();
    }
    if (t < nb) bsum[t] = s[t] - v;
}

__global__ void scan3_k(int* __restrict__ rowptr, const int* __restrict__ bsum, int N, int E) {
    int g = blockIdx.x * 256 + threadIdx.x;
    if (g < N) rowptr[g] += bsum[blockIdx.x];
    if (g == 0) rowptr[N] = E;
}

__global__ void scatter_k(const int* __restrict__ src, const int* __restrict__ dst,
                          const int* __restrict__ rowptr, int* __restrict__ cursor,
                          int* __restrict__ ecol, int E) {
    int e = blockIdx.x * blockDim.x + threadIdx.x;
    if (e >= E) return;
    int d = dst[e];
    int r = atomicSub(&cursor[d], 1);
    ecol[rowptr[d] + r - 1] = src[e];
}

// ---------- MFMA GEMM: C[M,Nfull] = A[M,K_] * B[K_,Nfull], all bf16, fp32 accum ----------
// block = 256 thr (4 waves); tile 128 rows x 64 cols; K staged in 128-chunks.
template <int K_>
__global__ __launch_bounds__(256)
void gemm_mfma_k(const unsigned short* __restrict__ A, const unsigned short* __restrict__ B,
                 __hip_bfloat16* __restrict__ C, int M, int Nfull) {
    constexpr int BKC = 128;
    constexpr int LDA = BKC + 8;                 // +8 bf16 pad: 2-way LDS conflict (free)
    __shared__ unsigned short As[128 * LDA];
    __shared__ unsigned short Bs[64 * LDA];
    int t = threadIdx.x;
    int row0 = blockIdx.x * 128;
    int col0 = blockIdx.y * 64;

    int wave = t >> 6, lane = t & 63;
    int wr = (wave >> 1) * 64, wc = (wave & 1) * 32;
    int m16 = lane & 15, quad = lane >> 4;

    f32x4 acc[4][2] = {};

    for (int k0 = 0; k0 < K_; k0 += BKC) {
        // stage A chunk: 128 rows x BKC cols, 16 B per thread-iter
        for (int i = t; i < 128 * BKC / 8; i += 256) {
            int r = i / (BKC / 8);
            int c = (i % (BKC / 8)) * 8;
            int gr = row0 + r;
            uint4 v = make_uint4(0u, 0u, 0u, 0u);
            if (gr < M) v = *(const uint4*)&A[(size_t)gr * K_ + k0 + c];
            *(uint4*)&As[r * LDA + c] = v;
        }
        // stage B chunk transposed: Bs[n][k] = B[(k0+k)*Nfull + col0+n]
        for (int i = t; i < 64 * BKC; i += 256) {
            int n = i % 64;
            int k = i / 64;
            unsigned short v = 0;
            if (col0 + n < Nfull) v = B[(size_t)(k0 + k) * Nfull + col0 + n];
            Bs[n * LDA + k] = v;
        }
        __syncthreads();

        for (int kk = 0; kk < BKC; kk += 32) {
            bf16x8 a[4], b[2];
            for (int mt = 0; mt < 4; ++mt)
                a[mt] = *(const bf16x8*)&As[(wr + mt * 16 + m16) * LDA + kk + quad * 8];
            for (int nt = 0; nt < 2; ++nt)
                b[nt] = *(const bf16x8*)&Bs[(wc + nt * 16 + m16) * LDA + kk + quad * 8];
            for (int mt = 0; mt < 4; ++mt)
                for (int nt = 0; nt < 2; ++nt)
                    acc[mt][nt] = __builtin_amdgcn_mfma_f32_16x16x32_bf16(
                        a[mt], b[nt], acc[mt][nt], 0, 0, 0);
        }
        __syncthreads();
    }

    // epilogue: D[row][col], col = lane&15, row = quad*4 + reg
    for (int mt = 0; mt < 4; ++mt)
        for (int nt = 0; nt < 2; ++nt)
            for (int r = 0; r < 4; ++r) {
                int gr = row0 + wr + mt * 16 + quad * 4 + r;
                int gc = col0 + wc + nt * 16 + m16;
                if (gr < M && gc < Nfull)
                    C[(size_t)gr * Nfull + gc] = __float2bfloat16(acc[mt][nt][r]);
            }
}

// ---------- attention coefficients ----------
__global__ void attn_k(const __hip_bfloat16* __restrict__ Hp, const void* __restrict__ al,
                       const void* __restrict__ ar, const int* __restrict__ flag,
                       float* __restrict__ el, float* __restrict__ er, int H, int F) {
    __shared__ float vl[256];
    __shared__ float vr[256];
    bool bf = (*flag != 0);
    int n = blockIdx.x, t = threadIdx.x;
    int HF = H * F;
    if (t < HF) {
        float v = __bfloat162float(Hp[(size_t)n * HF + t]);
        vl[t] = v * loadF(al, t, bf);
        vr[t] = v * loadF(ar, t, bf);
    }
    __syncthreads();
    if (t < H) {
        float sl = 0.f, sr = 0.f;
        int b = t * F;
        for (int f = 0; f < F; ++f) { sl += vl[b + f]; sr += vr[b + f]; }
        el[n * H + t] = sl;
        er[n * H + t] = sr;
    }
}

// ---------- CSR softmax-aggregation: one block per dst node ----------
template <int H, int F, int BLOCK, bool DOELU, typename TOUT>
__global__ void aggr_k(const int* __restrict__ rowptr, const int* __restrict__ ecol,
                       const float* __restrict__ el, const float* __restrict__ er,
                       const __hip_bfloat16* __restrict__ Hp, TOUT* __restrict__ out) {
    constexpr int HF = H * F;
    constexpr int G = BLOCK / H;
    constexpr int CAP = 64;
    __shared__ float s_m[H];
    __shared__ float s_s[H];
    __shared__ int s_src[CAP];
    __shared__ float s_a[CAP][H];
    int n = blockIdx.x, t = threadIdx.x;
    int beg = rowptr[n];
    int deg = rowptr[n + 1] - beg;

    int h = t / G, l = t % G;
    float er_h = er[n * H + h];
    float m = -1e30f;
    for (int i = l; i < deg; i += G) {
        int s = ecol[beg + i];
        float v = el[s * H + h] + er_h;
        v = (v >= 0.f) ? v : 0.2f * v;
        m = fmaxf(m, v);
    }
    for (int off = G / 2; off; off >>= 1) m = fmaxf(m, __shfl_down(m, off, G));
    m = __shfl(m, 0, G);
    float ssum = 0.f;
    for (int i = l; i < deg; i += G) {
        int s = ecol[beg + i];
        float v = el[s * H + h] + er_h;
        v = (v >= 0.f) ? v : 0.2f * v;
        ssum += expf(v - m);
    }
    for (int off = G / 2; off; off >>= 1) ssum += __shfl_down(ssum, off, G);
    if (l == 0) { s_m[h] = m; s_s[h] = ssum; }
    __syncthreads();

    float acc = 0.f;
    for (int base = 0; base < deg; base += CAP) {
        int cnt = min(CAP, deg - base);
        for (int idx = t; idx < cnt * H; idx += BLOCK) {
            int i = idx / H, h2 = idx % H;
            int s = ecol[beg + base + i];
            if (h2 == 0) s_src[i] = s;
            float v = el[s * H + h2] + er[n * H + h2];
            v = (v >= 0.f) ? v : 0.2f * v;
            s_a[i][h2] = expf(v - s_m[h2]) / (s_s[h2] + 1e-16f);
        }
        __syncthreads();
        if (t < HF) {
            int hh = t / F;
            for (int i = 0; i < cnt; ++i)
                acc += s_a[i][hh] * __bfloat162float(Hp[(size_t)s_src[i] * HF + t]);
        }
        __syncthreads();
    }
    if (t < HF) {
        float r = DOELU ? ((acc > 0.f) ? acc : expm1f(acc)) : acc;
        storeT(out, (size_t)n * HF + t, r);
    }
}

// ---------- log_softmax, dual-dtype output ----------
__global__ void logsm_k(const float* __restrict__ acc, void* __restrict__ outp,
                        const int* __restrict__ flag) {
    __shared__ float vals[40];
    __shared__ float lse;
    int n = blockIdx.x, t = threadIdx.x;
    if (t < 40) vals[t] = acc[(size_t)n * 40 + t];
    __syncthreads();
    if (t == 0) {
        float m = vals[0];
        for (int i = 1; i < 40; ++i) m = fmaxf(m, vals[i]);
        float s = 0.f;
        for (int i = 0; i < 40; ++i) s += expf(vals[i] - m);
        lse = m + logf(s);
    }
    __syncthreads();
    if (t < 40) {
        float r = vals[t] - lse;
        if (*flag) ((__hip_bfloat16*)outp)[(size_t)n * 40 + t] = __float2bfloat16(r);
        else       ((float*)outp)[(size_t)n * 40 + t] = r;
    }
}

extern "C" void kernel_launch(void* const* d_in, const int* in_sizes, int n_in,
                              void* d_out, int out_size, void* d_ws, size_t ws_size,
                              hipStream_t stream) {
    const int N = N_NODES, E = N_EDGES;
    const void* x   = d_in[0];
    const int* src  = (const int*)d_in[1];
    const int* dst  = (const int*)d_in[2];
    const void* W1  = d_in[3];
    const void* al1 = d_in[4];
    const void* ar1 = d_in[5];
    const void* W2  = d_in[6];
    const void* al2 = d_in[7];
    const void* ar2 = d_in[8];
    const void* Wo  = d_in[9];
    const void* alo = d_in[10];
    const void* aro = d_in[11];

    // workspace layout (~58.2 MB), 256-B aligned chunks
    char* w = (char*)d_ws;
    auto alloc = [&](size_t bytes) { void* p = (void*)w; w += (bytes + 255) & ~(size_t)255; return p; };
    int* flag      = (int*)alloc(4);
    int* rowptr    = (int*)alloc((size_t)(N + 1) * 4);
    int* cursor    = (int*)alloc((size_t)N * 4);
    int* bsum      = (int*)alloc(256 * 4);
    int* ecol      = (int*)alloc((size_t)E * 4);
    float* el      = (float*)alloc((size_t)N * 8 * 4);
    float* er      = (float*)alloc((size_t)N * 8 * 4);
    unsigned short* W1b = (unsigned short*)alloc((size_t)128 * 256 * 2);
    unsigned short* W2b = (unsigned short*)alloc((size_t)256 * 256 * 2);
    unsigned short* Wob = (unsigned short*)alloc((size_t)256 * 40 * 2);
    __hip_bfloat16* Hp   = (__hip_bfloat16*)alloc((size_t)N * 256 * 2);
    __hip_bfloat16* Hagg = (__hip_bfloat16*)alloc((size_t)N * 256 * 2);
    unsigned short* Xb = (unsigned short*)Hagg;  // alias: Xb dead once layer-1 gemm done
    float* Fout = (float*)Hagg;                  // alias: output-layer aggr result

    int EB = (E + 255) / 256;
    int NB = (N + 255) / 256;
    int MB = (N + 127) / 128;   // gemm row-blocks

    // dtype flag, bf16 conversions, CSR build
    detect_k<<<1, 64, 0, stream>>>((const unsigned short*)x, flag);
    cvt8_k<<<(N * 128 / 8 + 255) / 256, 256, 0, stream>>>(x, Xb, N * 128 / 8, flag);
    cvt8_k<<<(128 * 256 / 8 + 255) / 256, 256, 0, stream>>>(W1, W1b, 128 * 256 / 8, flag);
    cvt8_k<<<(256 * 256 / 8 + 255) / 256, 256, 0, stream>>>(W2, W2b, 256 * 256 / 8, flag);
    cvt8_k<<<(256 * 40 / 8 + 255) / 256, 256, 0, stream>>>(Wo, Wob, 256 * 40 / 8, flag);
    hipMemsetAsync(cursor, 0, (size_t)N * 4, stream);
    hist_k<<<EB, 256, 0, stream>>>(dst, cursor, E);
    scan1_k<<<NB, 256, 0, stream>>>(cursor, rowptr, bsum, N);
    scan2_k<<<1, 256, 0, stream>>>(bsum, NB);
    scan3_k<<<NB, 256, 0, stream>>>(rowptr, bsum, N, E);
    scatter_k<<<EB, 256, 0, stream>>>(src, dst, rowptr, cursor, ecol, E);

    // ---- layer 1: Xb[N,128] @ W1 -> [N,8,32], GAT, ELU ----
    gemm_mfma_k<128><<<dim3(MB, 4), 256, 0, stream>>>(Xb, W1b, Hp, N, 256);
    attn_k<<<N, 256, 0, stream>>>(Hp, al1, ar1, flag, el, er, 8, 32);
    aggr_k<8, 32, 256, true, __hip_bfloat16><<<N, 256, 0, stream>>>(rowptr, ecol, el, er, Hp, Hagg);

    // ---- layer 2: Hagg[N,256] @ W2 -> [N,8,32], GAT, ELU ----
    gemm_mfma_k<256><<<dim3(MB, 4), 256, 0, stream>>>((const unsigned short*)Hagg, W2b, Hp, N, 256);
    attn_k<<<N, 256, 0, stream>>>(Hp, al2, ar2, flag, el, er, 8, 32);
    aggr_k<8, 32, 256, true, __hip_bfloat16><<<N, 256, 0, stream>>>(rowptr, ecol, el, er, Hp, Hagg);

    // ---- output layer: Hagg[N,256] @ Wo -> [N,40], GAT(1 head), log_softmax ----
    gemm_mfma_k<256><<<dim3(MB, 1), 256, 0, stream>>>((const unsigned short*)Hagg, Wob, Hp, N, 40);
    attn_k<<<N, 64, 0, stream>>>(Hp, alo, aro, flag, el, er, 1, 40);
    aggr_k<1, 40, 64, false, float><<<N, 64, 0, stream>>>(rowptr, ecol, el, er, Hp, Fout);
    logsm_k<<<N, 64, 0, stream>>>(Fout, d_out, flag);
}

// Round 5
// 750.341 us; speedup vs baseline: 2.2577x; 1.0688x over previous
//
#include <hip/hip_runtime.h>
#include <hip/hip_bf16.h>

#define N_NODES 50000
#define N_EDGES 800000

typedef __bf16 bf16x8 __attribute__((ext_vector_type(8)));
typedef float f32x4 __attribute__((ext_vector_type(4)));

// ---------- dual-dtype load ----------
__device__ __forceinline__ float loadF(const void* p, size_t i, bool isbf) {
    return isbf ? __bfloat162float(((const __hip_bfloat16*)p)[i]) : ((const float*)p)[i];
}
__device__ __forceinline__ void storeT(__hip_bfloat16* p, size_t i, float v) { p[i] = __float2bfloat16(v); }
__device__ __forceinline__ void storeT(float* p, size_t i, float v) { p[i] = v; }

__device__ __forceinline__ float bfbits2f(unsigned short u) {
    return __uint_as_float(((unsigned)u) << 16);
}

// ---------- dtype detect: even-index uint16 words of x ----------
__global__ void detect_k(const unsigned short* __restrict__ xw, int* __restrict__ flag) {
    int t = threadIdx.x;  // 64 threads
    int cnt = 0;
    for (int i = t; i < 512; i += 64) {
        unsigned e = (xw[2 * i] >> 7) & 0xFFu;
        if (e >= 117u && e <= 134u) cnt++;
    }
    for (int off = 32; off; off >>= 1) cnt += __shfl_down(cnt, off, 64);
    if (t == 0) *flag = (cnt >= 256) ? 1 : 0;   // 1 = inputs are bf16
}

// ---------- convert n8*8 elements to bf16 (copy if already bf16) ----------
__global__ void cvt8_k(const void* __restrict__ in, unsigned short* __restrict__ out,
                       int n8, const int* __restrict__ flag) {
    int i = blockIdx.x * blockDim.x + threadIdx.x;
    if (i >= n8) return;
    if (*flag) {
        ((uint4*)out)[i] = ((const uint4*)in)[i];
    } else {
        const float* f = (const float*)in + (size_t)i * 8;
        unsigned short r[8];
        for (int j = 0; j < 8; ++j) {
            __hip_bfloat16 h = __float2bfloat16(f[j]);
            r[j] = *(unsigned short*)&h;
        }
        *(uint4*)(out + (size_t)i * 8) = *(uint4*)r;
    }
}

// ---------- CSR build ----------
__global__ void hist_k(const int* __restrict__ dst, int* __restrict__ cnt, int E) {
    int e = blockIdx.x * blockDim.x + threadIdx.x;
    if (e < E) atomicAdd(&cnt[dst[e]], 1);
}

__global__ void scan1_k(const int* __restrict__ deg, int* __restrict__ rowptr,
                        int* __restrict__ bsum, int N) {
    __shared__ int s[256];
    int t = threadIdx.x, g = blockIdx.x * 256 + t;
    int v = (g < N) ? deg[g] : 0;
    s[t] = v; __syncthreads();
    for (int off = 1; off < 256; off <<= 1) {
        int x = (t >= off) ? s[t - off] : 0;
        __syncthreads();
        s[t] += x;
        __syncthreads();
    }
    if (g < N) rowptr[g] = s[t] - v;
    if (t == 255) bsum[blockIdx.x] = s[255];
}

__global__ void scan2_k(int* __restrict__ bsum, int nb) {
    __shared__ int s[256];
    int t = threadIdx.x;
    int v = (t < nb) ? bsum[t] : 0;
    s[t] = v; __syncthreads();
    for (int off = 1; off < 256; off <<= 1) {
        int x = (t >= off) ? s[t - off] : 0;
        __syncthreads();
        s[t] += x;
        __syncthreads();
    }
    if (t < nb) bsum[t] = s[t] - v;
}

__global__ void scan3_k(int* __restrict__ rowptr, const int* __restrict__ bsum, int N, int E) {
    int g = blockIdx.x * 256 + threadIdx.x;
    if (g < N) rowptr[g] += bsum[blockIdx.x];
    if (g == 0) rowptr[N] = E;
}

__global__ void scatter_k(const int* __restrict__ src, const int* __restrict__ dst,
                          const int* __restrict__ rowptr, int* __restrict__ cursor,
                          int* __restrict__ ecol, int E) {
    int e = blockIdx.x * blockDim.x + threadIdx.x;
    if (e >= E) return;
    int d = dst[e];
    int r = atomicSub(&cursor[d], 1);
    ecol[rowptr[d] + r - 1] = src[e];
}

// ---------- MFMA GEMM: C[M,Nfull] = A[M,K_] * B[K_,Nfull], all bf16, fp32 accum ----------
template <int K_>
__global__ __launch_bounds__(256)
void gemm_mfma_k(const unsigned short* __restrict__ A, const unsigned short* __restrict__ B,
                 __hip_bfloat16* __restrict__ C, int M, int Nfull) {
    constexpr int BKC = 128;
    constexpr int LDA = BKC + 8;
    __shared__ unsigned short As[128 * LDA];
    __shared__ unsigned short Bs[64 * LDA];
    int t = threadIdx.x;
    int row0 = blockIdx.x * 128;
    int col0 = blockIdx.y * 64;

    int wave = t >> 6, lane = t & 63;
    int wr = (wave >> 1) * 64, wc = (wave & 1) * 32;
    int m16 = lane & 15, quad = lane >> 4;

    f32x4 acc[4][2] = {};

    for (int k0 = 0; k0 < K_; k0 += BKC) {
        for (int i = t; i < 128 * BKC / 8; i += 256) {
            int r = i / (BKC / 8);
            int c = (i % (BKC / 8)) * 8;
            int gr = row0 + r;
            uint4 v = make_uint4(0u, 0u, 0u, 0u);
            if (gr < M) v = *(const uint4*)&A[(size_t)gr * K_ + k0 + c];
            *(uint4*)&As[r * LDA + c] = v;
        }
        for (int i = t; i < 64 * BKC; i += 256) {
            int n = i % 64;
            int k = i / 64;
            unsigned short v = 0;
            if (col0 + n < Nfull) v = B[(size_t)(k0 + k) * Nfull + col0 + n];
            Bs[n * LDA + k] = v;
        }
        __syncthreads();

        for (int kk = 0; kk < BKC; kk += 32) {
            bf16x8 a[4], b[2];
            for (int mt = 0; mt < 4; ++mt)
                a[mt] = *(const bf16x8*)&As[(wr + mt * 16 + m16) * LDA + kk + quad * 8];
            for (int nt = 0; nt < 2; ++nt)
                b[nt] = *(const bf16x8*)&Bs[(wc + nt * 16 + m16) * LDA + kk + quad * 8];
            for (int mt = 0; mt < 4; ++mt)
                for (int nt = 0; nt < 2; ++nt)
                    acc[mt][nt] = __builtin_amdgcn_mfma_f32_16x16x32_bf16(
                        a[mt], b[nt], acc[mt][nt], 0, 0, 0);
        }
        __syncthreads();
    }

    for (int mt = 0; mt < 4; ++mt)
        for (int nt = 0; nt < 2; ++nt)
            for (int r = 0; r < 4; ++r) {
                int gr = row0 + wr + mt * 16 + quad * 4 + r;
                int gc = col0 + wc + nt * 16 + m16;
                if (gr < M && gc < Nfull)
                    C[(size_t)gr * Nfull + gc] = __float2bfloat16(acc[mt][nt][r]);
            }
}

// ---------- attention coefficients ----------
__global__ void attn_k(const __hip_bfloat16* __restrict__ Hp, const void* __restrict__ al,
                       const void* __restrict__ ar, const int* __restrict__ flag,
                       float* __restrict__ el, float* __restrict__ er, int H, int F) {
    __shared__ float vl[256];
    __shared__ float vr[256];
    bool bf = (*flag != 0);
    int n = blockIdx.x, t = threadIdx.x;
    int HF = H * F;
    if (t < HF) {
        float v = __bfloat162float(Hp[(size_t)n * HF + t]);
        vl[t] = v * loadF(al, t, bf);
        vr[t] = v * loadF(ar, t, bf);
    }
    __syncthreads();
    if (t < H) {
        float sl = 0.f, sr = 0.f;
        int b = t * F;
        for (int f = 0; f < F; ++f) { sl += vl[b + f]; sr += vr[b + f]; }
        el[n * H + t] = sl;
        er[n * H + t] = sr;
    }
}

// ---------- vectorized CSR softmax-aggregation for H=8, F=32 (HF=256) ----------
// phase B: slice = t&31 handles 8 contiguous features (uint4 load), egrp = t>>5
// processes every 8th edge; per-thread acc[8] reduced across egrps via LDS.
template <bool DOELU>
__global__ __launch_bounds__(256)
void aggr8_k(const int* __restrict__ rowptr, const int* __restrict__ ecol,
             const float* __restrict__ el, const float* __restrict__ er,
             const __hip_bfloat16* __restrict__ Hp, __hip_bfloat16* __restrict__ out) {
    constexpr int H = 8, CAP = 32, G = 32;
    __shared__ float s_m[H];
    __shared__ float s_s[H];
    __shared__ int s_src[CAP];
    __shared__ float s_a[CAP][H];
    __shared__ float s_red[8][256];
    int n = blockIdx.x, t = threadIdx.x;
    int beg = rowptr[n];
    int deg = rowptr[n + 1] - beg;

    // phase A: per-head max then sum-of-exp (8 heads x 32 lanes)
    int h = t / G, l = t % G;
    float er_h = er[n * H + h];
    float m = -1e30f;
    for (int i = l; i < deg; i += G) {
        int s = ecol[beg + i];
        float v = el[s * H + h] + er_h;
        v = (v >= 0.f) ? v : 0.2f * v;
        m = fmaxf(m, v);
    }
    for (int off = G / 2; off; off >>= 1) m = fmaxf(m, __shfl_down(m, off, G));
    m = __shfl(m, 0, G);
    float ssum = 0.f;
    for (int i = l; i < deg; i += G) {
        int s = ecol[beg + i];
        float v = el[s * H + h] + er_h;
        v = (v >= 0.f) ? v : 0.2f * v;
        ssum += expf(v - m);
    }
    for (int off = G / 2; off; off >>= 1) ssum += __shfl_down(ssum, off, G);
    if (l == 0) { s_m[h] = m; s_s[h] = ssum; }
    __syncthreads();

    // phase B
    int slice = t & 31, egrp = t >> 5;
    int hh = slice >> 2;               // head of features [slice*8, slice*8+8)
    float acc[8] = {0.f, 0.f, 0.f, 0.f, 0.f, 0.f, 0.f, 0.f};
    for (int base = 0; base < deg; base += CAP) {
        int cnt = min(CAP, deg - base);
        for (int idx = t; idx < cnt * H; idx += 256) {
            int i = idx >> 3, h2 = idx & 7;
            int s = ecol[beg + base + i];
            if (h2 == 0) s_src[i] = s;
            float v = el[s * H + h2] + er[n * H + h2];
            v = (v >= 0.f) ? v : 0.2f * v;
            s_a[i][h2] = expf(v - s_m[h2]) / (s_s[h2] + 1e-16f);
        }
        __syncthreads();
        for (int i = egrp; i < cnt; i += 8) {
            uint4 v = *(const uint4*)((const unsigned short*)Hp +
                                      (size_t)s_src[i] * 256 + slice * 8);
            float a = s_a[i][hh];
            unsigned short u[8];
            *(uint4*)u = v;
            for (int j = 0; j < 8; ++j) acc[j] += a * bfbits2f(u[j]);
        }
        __syncthreads();
    }

    // reduce across the 8 edge-groups
    for (int j = 0; j < 8; ++j) s_red[egrp][slice * 8 + j] = acc[j];
    __syncthreads();
    float sum = 0.f;
    for (int g = 0; g < 8; ++g) sum += s_red[g][t];
    float r = DOELU ? ((sum > 0.f) ? sum : expm1f(sum)) : sum;
    out[(size_t)n * 256 + t] = __float2bfloat16(r);
}

// ---------- generic CSR softmax-aggregation (used for output layer) ----------
template <int H, int F, int BLOCK, bool DOELU, typename TOUT>
__global__ void aggr_k(const int* __restrict__ rowptr, const int* __restrict__ ecol,
                       const float* __restrict__ el, const float* __restrict__ er,
                       const __hip_bfloat16* __restrict__ Hp, TOUT* __restrict__ out) {
    constexpr int HF = H * F;
    constexpr int G = BLOCK / H;
    constexpr int CAP = 64;
    __shared__ float s_m[H];
    __shared__ float s_s[H];
    __shared__ int s_src[CAP];
    __shared__ float s_a[CAP][H];
    int n = blockIdx.x, t = threadIdx.x;
    int beg = rowptr[n];
    int deg = rowptr[n + 1] - beg;

    int h = t / G, l = t % G;
    float er_h = er[n * H + h];
    float m = -1e30f;
    for (int i = l; i < deg; i += G) {
        int s = ecol[beg + i];
        float v = el[s * H + h] + er_h;
        v = (v >= 0.f) ? v : 0.2f * v;
        m = fmaxf(m, v);
    }
    for (int off = G / 2; off; off >>= 1) m = fmaxf(m, __shfl_down(m, off, G));
    m = __shfl(m, 0, G);
    float ssum = 0.f;
    for (int i = l; i < deg; i += G) {
        int s = ecol[beg + i];
        float v = el[s * H + h] + er_h;
        v = (v >= 0.f) ? v : 0.2f * v;
        ssum += expf(v - m);
    }
    for (int off = G / 2; off; off >>= 1) ssum += __shfl_down(ssum, off, G);
    if (l == 0) { s_m[h] = m; s_s[h] = ssum; }
    __syncthreads();

    float acc = 0.f;
    for (int base = 0; base < deg; base += CAP) {
        int cnt = min(CAP, deg - base);
        for (int idx = t; idx < cnt * H; idx += BLOCK) {
            int i = idx / H, h2 = idx % H;
            int s = ecol[beg + base + i];
            if (h2 == 0) s_src[i] = s;
            float v = el[s * H + h2] + er[n * H + h2];
            v = (v >= 0.f) ? v : 0.2f * v;
            s_a[i][h2] = expf(v - s_m[h2]) / (s_s[h2] + 1e-16f);
        }
        __syncthreads();
        if (t < HF) {
            int hh = t / F;
            for (int i = 0; i < cnt; ++i)
                acc += s_a[i][hh] * __bfloat162float(Hp[(size_t)s_src[i] * HF + t]);
        }
        __syncthreads();
    }
    if (t < HF) {
        float r = DOELU ? ((acc > 0.f) ? acc : expm1f(acc)) : acc;
        storeT(out, (size_t)n * HF + t, r);
    }
}

// ---------- log_softmax, dual-dtype output ----------
__global__ void logsm_k(const float* __restrict__ acc, void* __restrict__ outp,
                        const int* __restrict__ flag) {
    __shared__ float vals[40];
    __shared__ float lse;
    int n = blockIdx.x, t = threadIdx.x;
    if (t < 40) vals[t] = acc[(size_t)n * 40 + t];
    __syncthreads();
    if (t == 0) {
        float m = vals[0];
        for (int i = 1; i < 40; ++i) m = fmaxf(m, vals[i]);
        float s = 0.f;
        for (int i = 0; i < 40; ++i) s += expf(vals[i] - m);
        lse = m + logf(s);
    }
    __syncthreads();
    if (t < 40) {
        float r = vals[t] - lse;
        if (*flag) ((__hip_bfloat16*)outp)[(size_t)n * 40 + t] = __float2bfloat16(r);
        else       ((float*)outp)[(size_t)n * 40 + t] = r;
    }
}

extern "C" void kernel_launch(void* const* d_in, const int* in_sizes, int n_in,
                              void* d_out, int out_size, void* d_ws, size_t ws_size,
                              hipStream_t stream) {
    const int N = N_NODES, E = N_EDGES;
    const void* x   = d_in[0];
    const int* src  = (const int*)d_in[1];
    const int* dst  = (const int*)d_in[2];
    const void* W1  = d_in[3];
    const void* al1 = d_in[4];
    const void* ar1 = d_in[5];
    const void* W2  = d_in[6];
    const void* al2 = d_in[7];
    const void* ar2 = d_in[8];
    const void* Wo  = d_in[9];
    const void* alo = d_in[10];
    const void* aro = d_in[11];

    // workspace layout (~58.2 MB), 256-B aligned chunks
    char* w = (char*)d_ws;
    auto alloc = [&](size_t bytes) { void* p = (void*)w; w += (bytes + 255) & ~(size_t)255; return p; };
    int* flag      = (int*)alloc(4);
    int* rowptr    = (int*)alloc((size_t)(N + 1) * 4);
    int* cursor    = (int*)alloc((size_t)N * 4);
    int* bsum      = (int*)alloc(256 * 4);
    int* ecol      = (int*)alloc((size_t)E * 4);
    float* el      = (float*)alloc((size_t)N * 8 * 4);
    float* er      = (float*)alloc((size_t)N * 8 * 4);
    unsigned short* W1b = (unsigned short*)alloc((size_t)128 * 256 * 2);
    unsigned short* W2b = (unsigned short*)alloc((size_t)256 * 256 * 2);
    unsigned short* Wob = (unsigned short*)alloc((size_t)256 * 40 * 2);
    __hip_bfloat16* Hp   = (__hip_bfloat16*)alloc((size_t)N * 256 * 2);
    __hip_bfloat16* Hagg = (__hip_bfloat16*)alloc((size_t)N * 256 * 2);
    unsigned short* Xb = (unsigned short*)Hagg;
    float* Fout = (float*)Hagg;

    int EB = (E + 255) / 256;
    int NB = (N + 255) / 256;
    int MB = (N + 127) / 128;

    detect_k<<<1, 64, 0, stream>>>((const unsigned short*)x, flag);
    cvt8_k<<<(N * 128 / 8 + 255) / 256, 256, 0, stream>>>(x, Xb, N * 128 / 8, flag);
    cvt8_k<<<(128 * 256 / 8 + 255) / 256, 256, 0, stream>>>(W1, W1b, 128 * 256 / 8, flag);
    cvt8_k<<<(256 * 256 / 8 + 255) / 256, 256, 0, stream>>>(W2, W2b, 256 * 256 / 8, flag);
    cvt8_k<<<(256 * 40 / 8 + 255) / 256, 256, 0, stream>>>(Wo, Wob, 256 * 40 / 8, flag);
    hipMemsetAsync(cursor, 0, (size_t)N * 4, stream);
    hist_k<<<EB, 256, 0, stream>>>(dst, cursor, E);
    scan1_k<<<NB, 256, 0, stream>>>(cursor, rowptr, bsum, N);
    scan2_k<<<1, 256, 0, stream>>>(bsum, NB);
    scan3_k<<<NB, 256, 0, stream>>>(rowptr, bsum, N, E);
    scatter_k<<<EB, 256, 0, stream>>>(src, dst, rowptr, cursor, ecol, E);

    // ---- layer 1 ----
    gemm_mfma_k<128><<<dim3(MB, 4), 256, 0, stream>>>(Xb, W1b, Hp, N, 256);
    attn_k<<<N, 256, 0, stream>>>(Hp, al1, ar1, flag, el, er, 8, 32);
    aggr8_k<true><<<N, 256, 0, stream>>>(rowptr, ecol, el, er, Hp, Hagg);

    // ---- layer 2 ----
    gemm_mfma_k<256><<<dim3(MB, 4), 256, 0, stream>>>((const unsigned short*)Hagg, W2b, Hp, N, 256);
    attn_k<<<N, 256, 0, stream>>>(Hp, al2, ar2, flag, el, er, 8, 32);
    aggr8_k<true><<<N, 256, 0, stream>>>(rowptr, ecol, el, er, Hp, Hagg);

    // ---- output layer ----
    gemm_mfma_k<256><<<dim3(MB, 1), 256, 0, stream>>>((const unsigned short*)Hagg, Wob, Hp, N, 40);
    attn_k<<<N, 64, 0, stream>>>(Hp, alo, aro, flag, el, er, 1, 40);
    aggr_k<1, 40, 64, false, float><<<N, 64, 0, stream>>>(rowptr, ecol, el, er, Hp, Fout);
    logsm_k<<<N, 64, 0, stream>>>(Fout, d_out, flag);
}

// Round 6
// 697.961 us; speedup vs baseline: 2.4272x; 1.0750x over previous
//
#include <hip/hip_runtime.h>
#include <hip/hip_bf16.h>

#define N_NODES 50000
#define N_EDGES 800000

typedef __bf16 bf16x8 __attribute__((ext_vector_type(8)));
typedef float f32x4 __attribute__((ext_vector_type(4)));

// ---------- dual-dtype load ----------
__device__ __forceinline__ float loadF(const void* p, size_t i, bool isbf) {
    return isbf ? __bfloat162float(((const __hip_bfloat16*)p)[i]) : ((const float*)p)[i];
}
__device__ __forceinline__ void storeT(__hip_bfloat16* p, size_t i, float v) { p[i] = __float2bfloat16(v); }
__device__ __forceinline__ void storeT(float* p, size_t i, float v) { p[i] = v; }

__device__ __forceinline__ float bfbits2f(unsigned short u) {
    return __uint_as_float(((unsigned)u) << 16);
}

// ---------- dtype detect: even-index uint16 words of x ----------
__global__ void detect_k(const unsigned short* __restrict__ xw, int* __restrict__ flag) {
    int t = threadIdx.x;  // 64 threads
    int cnt = 0;
    for (int i = t; i < 512; i += 64) {
        unsigned e = (xw[2 * i] >> 7) & 0xFFu;
        if (e >= 117u && e <= 134u) cnt++;
    }
    for (int off = 32; off; off >>= 1) cnt += __shfl_down(cnt, off, 64);
    if (t == 0) *flag = (cnt >= 256) ? 1 : 0;   // 1 = inputs are bf16
}

// ---------- convert n8*8 elements to bf16 (copy if already bf16) ----------
__global__ void cvt8_k(const void* __restrict__ in, unsigned short* __restrict__ out,
                       int n8, const int* __restrict__ flag) {
    int i = blockIdx.x * blockDim.x + threadIdx.x;
    if (i >= n8) return;
    if (*flag) {
        ((uint4*)out)[i] = ((const uint4*)in)[i];
    } else {
        const float* f = (const float*)in + (size_t)i * 8;
        unsigned short r[8];
        for (int j = 0; j < 8; ++j) {
            __hip_bfloat16 h = __float2bfloat16(f[j]);
            r[j] = *(unsigned short*)&h;
        }
        *(uint4*)(out + (size_t)i * 8) = *(uint4*)r;
    }
}

// ---------- CSR build ----------
__global__ void hist_k(const int* __restrict__ dst, int* __restrict__ cnt, int E) {
    int e = blockIdx.x * blockDim.x + threadIdx.x;
    if (e < E) atomicAdd(&cnt[dst[e]], 1);
}

__global__ void scan1_k(const int* __restrict__ deg, int* __restrict__ rowptr,
                        int* __restrict__ bsum, int N) {
    __shared__ int s[256];
    int t = threadIdx.x, g = blockIdx.x * 256 + t;
    int v = (g < N) ? deg[g] : 0;
    s[t] = v; __syncthreads();
    for (int off = 1; off < 256; off <<= 1) {
        int x = (t >= off) ? s[t - off] : 0;
        __syncthreads();
        s[t] += x;
        __syncthreads();
    }
    if (g < N) rowptr[g] = s[t] - v;
    if (t == 255) bsum[blockIdx.x] = s[255];
}

__global__ void scan2_k(int* __restrict__ bsum, int nb) {
    __shared__ int s[256];
    int t = threadIdx.x;
    int v = (t < nb) ? bsum[t] : 0;
    s[t] = v; __syncthreads();
    for (int off = 1; off < 256; off <<= 1) {
        int x = (t >= off) ? s[t - off] : 0;
        __syncthreads();
        s[t] += x;
        __syncthreads();
    }
    if (t < nb) bsum[t] = s[t] - v;
}

__global__ void scan3_k(int* __restrict__ rowptr, const int* __restrict__ bsum, int N, int E) {
    int g = blockIdx.x * 256 + threadIdx.x;
    if (g < N) rowptr[g] += bsum[blockIdx.x];
    if (g == 0) rowptr[N] = E;
}

__global__ void scatter_k(const int* __restrict__ src, const int* __restrict__ dst,
                          const int* __restrict__ rowptr, int* __restrict__ cursor,
                          int* __restrict__ ecol, int E) {
    int e = blockIdx.x * blockDim.x + threadIdx.x;
    if (e >= E) return;
    int d = dst[e];
    int r = atomicSub(&cursor[d], 1);
    ecol[rowptr[d] + r - 1] = src[e];
}

// ---------- MFMA GEMM: C[M,Nfull] = A[M,K_] * B[K_,Nfull], all bf16, fp32 accum ----------
template <int K_>
__global__ __launch_bounds__(256)
void gemm_mfma_k(const unsigned short* __restrict__ A, const unsigned short* __restrict__ B,
                 __hip_bfloat16* __restrict__ C, int M, int Nfull) {
    constexpr int BKC = 128;
    constexpr int LDA = BKC + 8;
    __shared__ unsigned short As[128 * LDA];
    __shared__ unsigned short Bs[64 * LDA];
    int t = threadIdx.x;
    int row0 = blockIdx.x * 128;
    int col0 = blockIdx.y * 64;

    int wave = t >> 6, lane = t & 63;
    int wr = (wave >> 1) * 64, wc = (wave & 1) * 32;
    int m16 = lane & 15, quad = lane >> 4;

    f32x4 acc[4][2] = {};

    for (int k0 = 0; k0 < K_; k0 += BKC) {
        for (int i = t; i < 128 * BKC / 8; i += 256) {
            int r = i / (BKC / 8);
            int c = (i % (BKC / 8)) * 8;
            int gr = row0 + r;
            uint4 v = make_uint4(0u, 0u, 0u, 0u);
            if (gr < M) v = *(const uint4*)&A[(size_t)gr * K_ + k0 + c];
            *(uint4*)&As[r * LDA + c] = v;
        }
        for (int i = t; i < 64 * BKC; i += 256) {
            int n = i % 64;
            int k = i / 64;
            unsigned short v = 0;
            if (col0 + n < Nfull) v = B[(size_t)(k0 + k) * Nfull + col0 + n];
            Bs[n * LDA + k] = v;
        }
        __syncthreads();

        for (int kk = 0; kk < BKC; kk += 32) {
            bf16x8 a[4], b[2];
            for (int mt = 0; mt < 4; ++mt)
                a[mt] = *(const bf16x8*)&As[(wr + mt * 16 + m16) * LDA + kk + quad * 8];
            for (int nt = 0; nt < 2; ++nt)
                b[nt] = *(const bf16x8*)&Bs[(wc + nt * 16 + m16) * LDA + kk + quad * 8];
            for (int mt = 0; mt < 4; ++mt)
                for (int nt = 0; nt < 2; ++nt)
                    acc[mt][nt] = __builtin_amdgcn_mfma_f32_16x16x32_bf16(
                        a[mt], b[nt], acc[mt][nt], 0, 0, 0);
        }
        __syncthreads();
    }

    for (int mt = 0; mt < 4; ++mt)
        for (int nt = 0; nt < 2; ++nt)
            for (int r = 0; r < 4; ++r) {
                int gr = row0 + wr + mt * 16 + quad * 4 + r;
                int gc = col0 + wc + nt * 16 + m16;
                if (gr < M && gc < Nfull)
                    C[(size_t)gr * Nfull + gc] = __float2bfloat16(acc[mt][nt][r]);
            }
}

// ---------- attention coefficients ----------
__global__ void attn_k(const __hip_bfloat16* __restrict__ Hp, const void* __restrict__ al,
                       const void* __restrict__ ar, const int* __restrict__ flag,
                       float* __restrict__ el, float* __restrict__ er, int H, int F) {
    __shared__ float vl[256];
    __shared__ float vr[256];
    bool bf = (*flag != 0);
    int n = blockIdx.x, t = threadIdx.x;
    int HF = H * F;
    if (t < HF) {
        float v = __bfloat162float(Hp[(size_t)n * HF + t]);
        vl[t] = v * loadF(al, t, bf);
        vr[t] = v * loadF(ar, t, bf);
    }
    __syncthreads();
    if (t < H) {
        float sl = 0.f, sr = 0.f;
        int b = t * F;
        for (int f = 0; f < F; ++f) { sl += vl[b + f]; sr += vr[b + f]; }
        el[n * H + t] = sl;
        er[n * H + t] = sr;
    }
}

// ---------- half-wave CSR softmax-aggregation for H=8, F=32 (HF=256) ----------
// 32 lanes per node, 8 nodes per 256-block. No LDS, no __syncthreads.
// Phase A: lane=(h=l&7, q=l>>3) computes per-head max then sum via shfl_xor.
// Phase B: lane l owns feats [8l,8l+8); out = (sum_i ex_i * h_i) / s, then ELU.
template <bool DOELU>
__global__ __launch_bounds__(256)
void aggr_hw_k(const int* __restrict__ rowptr, const int* __restrict__ ecol,
               const float* __restrict__ el, const float* __restrict__ er,
               const __hip_bfloat16* __restrict__ Hp, __hip_bfloat16* __restrict__ out, int N) {
    int t = threadIdx.x;
    int hw = t >> 5, l = t & 31;
    int n = blockIdx.x * 8 + hw;
    if (n >= N) return;
    int beg = rowptr[n], deg = rowptr[n + 1] - beg;

    // phase A: per-head max and sum of exp
    int h = l & 7, q = l >> 3;
    float er_h = er[n * 8 + h];
    float m = -1e30f;
    for (int i = q; i < deg; i += 4) {
        int s = ecol[beg + i];
        float v = el[s * 8 + h] + er_h;
        v = (v >= 0.f) ? v : 0.2f * v;
        m = fmaxf(m, v);
    }
    m = fmaxf(m, __shfl_xor(m, 8, 32));
    m = fmaxf(m, __shfl_xor(m, 16, 32));
    float ss = 0.f;
    for (int i = q; i < deg; i += 4) {
        int s = ecol[beg + i];
        float v = el[s * 8 + h] + er_h;
        v = (v >= 0.f) ? v : 0.2f * v;
        ss += __expf(v - m);
    }
    ss += __shfl_xor(ss, 8, 32);
    ss += __shfl_xor(ss, 16, 32);

    // phase B: gather + weighted accumulate; normalize at the end
    int hh = l >> 2;                      // head of feats [8l, 8l+8)
    float m_hh = __shfl(m, hh, 32);
    float s_hh = __shfl(ss, hh, 32);
    float er_hh = __shfl(er_h, hh, 32);
    float inv_s = 1.f / (s_hh + 1e-16f);
    float acc[8] = {0.f, 0.f, 0.f, 0.f, 0.f, 0.f, 0.f, 0.f};
    for (int i = 0; i < deg; ++i) {
        int s = ecol[beg + i];
        float v = el[s * 8 + hh] + er_hh;
        v = (v >= 0.f) ? v : 0.2f * v;
        float ex = __expf(v - m_hh);
        uint4 r = *(const uint4*)((const unsigned short*)Hp + (size_t)s * 256 + l * 8);
        unsigned short u[8];
        *(uint4*)u = r;
        for (int j = 0; j < 8; ++j) acc[j] += ex * bfbits2f(u[j]);
    }
    unsigned short o[8];
    for (int j = 0; j < 8; ++j) {
        float vv = acc[j] * inv_s;
        if (DOELU) vv = (vv > 0.f) ? vv : expm1f(vv);
        __hip_bfloat16 hb = __float2bfloat16(vv);
        o[j] = *(unsigned short*)&hb;
    }
    *(uint4*)((unsigned short*)out + (size_t)n * 256 + l * 8) = *(uint4*)o;
}

// ---------- generic CSR softmax-aggregation (used for output layer) ----------
template <int H, int F, int BLOCK, bool DOELU, typename TOUT>
__global__ void aggr_k(const int* __restrict__ rowptr, const int* __restrict__ ecol,
                       const float* __restrict__ el, const float* __restrict__ er,
                       const __hip_bfloat16* __restrict__ Hp, TOUT* __restrict__ out) {
    constexpr int HF = H * F;
    constexpr int G = BLOCK / H;
    constexpr int CAP = 64;
    __shared__ float s_m[H];
    __shared__ float s_s[H];
    __shared__ int s_src[CAP];
    __shared__ float s_a[CAP][H];
    int n = blockIdx.x, t = threadIdx.x;
    int beg = rowptr[n];
    int deg = rowptr[n + 1] - beg;

    int h = t / G, l = t % G;
    float er_h = er[n * H + h];
    float m = -1e30f;
    for (int i = l; i < deg; i += G) {
        int s = ecol[beg + i];
        float v = el[s * H + h] + er_h;
        v = (v >= 0.f) ? v : 0.2f * v;
        m = fmaxf(m, v);
    }
    for (int off = G / 2; off; off >>= 1) m = fmaxf(m, __shfl_down(m, off, G));
    m = __shfl(m, 0, G);
    float ssum = 0.f;
    for (int i = l; i < deg; i += G) {
        int s = ecol[beg + i];
        float v = el[s * H + h] + er_h;
        v = (v >= 0.f) ? v : 0.2f * v;
        ssum += expf(v - m);
    }
    for (int off = G / 2; off; off >>= 1) ssum += __shfl_down(ssum, off, G);
    if (l == 0) { s_m[h] = m; s_s[h] = ssum; }
    __syncthreads();

    float acc = 0.f;
    for (int base = 0; base < deg; base += CAP) {
        int cnt = min(CAP, deg - base);
        for (int idx = t; idx < cnt * H; idx += BLOCK) {
            int i = idx / H, h2 = idx % H;
            int s = ecol[beg + base + i];
            if (h2 == 0) s_src[i] = s;
            float v = el[s * H + h2] + er[n * H + h2];
            v = (v >= 0.f) ? v : 0.2f * v;
            s_a[i][h2] = expf(v - s_m[h2]) / (s_s[h2] + 1e-16f);
        }
        __syncthreads();
        if (t < HF) {
            int hh = t / F;
            for (int i = 0; i < cnt; ++i)
                acc += s_a[i][hh] * __bfloat162float(Hp[(size_t)s_src[i] * HF + t]);
        }
        __syncthreads();
    }
    if (t < HF) {
        float r = DOELU ? ((acc > 0.f) ? acc : expm1f(acc)) : acc;
        storeT(out, (size_t)n * HF + t, r);
    }
}

// ---------- log_softmax, dual-dtype output ----------
__global__ void logsm_k(const float* __restrict__ acc, void* __restrict__ outp,
                        const int* __restrict__ flag) {
    __shared__ float vals[40];
    __shared__ float lse;
    int n = blockIdx.x, t = threadIdx.x;
    if (t < 40) vals[t] = acc[(size_t)n * 40 + t];
    __syncthreads();
    if (t == 0) {
        float m = vals[0];
        for (int i = 1; i < 40; ++i) m = fmaxf(m, vals[i]);
        float s = 0.f;
        for (int i = 0; i < 40; ++i) s += expf(vals[i] - m);
        lse = m + logf(s);
    }
    __syncthreads();
    if (t < 40) {
        float r = vals[t] - lse;
        if (*flag) ((__hip_bfloat16*)outp)[(size_t)n * 40 + t] = __float2bfloat16(r);
        else       ((float*)outp)[(size_t)n * 40 + t] = r;
    }
}

extern "C" void kernel_launch(void* const* d_in, const int* in_sizes, int n_in,
                              void* d_out, int out_size, void* d_ws, size_t ws_size,
                              hipStream_t stream) {
    const int N = N_NODES, E = N_EDGES;
    const void* x   = d_in[0];
    const int* src  = (const int*)d_in[1];
    const int* dst  = (const int*)d_in[2];
    const void* W1  = d_in[3];
    const void* al1 = d_in[4];
    const void* ar1 = d_in[5];
    const void* W2  = d_in[6];
    const void* al2 = d_in[7];
    const void* ar2 = d_in[8];
    const void* Wo  = d_in[9];
    const void* alo = d_in[10];
    const void* aro = d_in[11];

    // workspace layout (~58.2 MB), 256-B aligned chunks
    char* w = (char*)d_ws;
    auto alloc = [&](size_t bytes) { void* p = (void*)w; w += (bytes + 255) & ~(size_t)255; return p; };
    int* flag      = (int*)alloc(4);
    int* rowptr    = (int*)alloc((size_t)(N + 1) * 4);
    int* cursor    = (int*)alloc((size_t)N * 4);
    int* bsum      = (int*)alloc(256 * 4);
    int* ecol      = (int*)alloc((size_t)E * 4);
    float* el      = (float*)alloc((size_t)N * 8 * 4);
    float* er      = (float*)alloc((size_t)N * 8 * 4);
    unsigned short* W1b = (unsigned short*)alloc((size_t)128 * 256 * 2);
    unsigned short* W2b = (unsigned short*)alloc((size_t)256 * 256 * 2);
    unsigned short* Wob = (unsigned short*)alloc((size_t)256 * 40 * 2);
    __hip_bfloat16* Hp   = (__hip_bfloat16*)alloc((size_t)N * 256 * 2);
    __hip_bfloat16* Hagg = (__hip_bfloat16*)alloc((size_t)N * 256 * 2);
    unsigned short* Xb = (unsigned short*)Hagg;
    float* Fout = (float*)Hagg;

    int EB = (E + 255) / 256;
    int NB = (N + 255) / 256;
    int MB = (N + 127) / 128;
    int AB = (N + 7) / 8;      // aggr_hw blocks (8 nodes each)

    detect_k<<<1, 64, 0, stream>>>((const unsigned short*)x, flag);
    cvt8_k<<<(N * 128 / 8 + 255) / 256, 256, 0, stream>>>(x, Xb, N * 128 / 8, flag);
    cvt8_k<<<(128 * 256 / 8 + 255) / 256, 256, 0, stream>>>(W1, W1b, 128 * 256 / 8, flag);
    cvt8_k<<<(256 * 256 / 8 + 255) / 256, 256, 0, stream>>>(W2, W2b, 256 * 256 / 8, flag);
    cvt8_k<<<(256 * 40 / 8 + 255) / 256, 256, 0, stream>>>(Wo, Wob, 256 * 40 / 8, flag);
    hipMemsetAsync(cursor, 0, (size_t)N * 4, stream);
    hist_k<<<EB, 256, 0, stream>>>(dst, cursor, E);
    scan1_k<<<NB, 256, 0, stream>>>(cursor, rowptr, bsum, N);
    scan2_k<<<1, 256, 0, stream>>>(bsum, NB);
    scan3_k<<<NB, 256, 0, stream>>>(rowptr, bsum, N, E);
    scatter_k<<<EB, 256, 0, stream>>>(src, dst, rowptr, cursor, ecol, E);

    // ---- layer 1 ----
    gemm_mfma_k<128><<<dim3(MB, 4), 256, 0, stream>>>(Xb, W1b, Hp, N, 256);
    attn_k<<<N, 256, 0, stream>>>(Hp, al1, ar1, flag, el, er, 8, 32);
    aggr_hw_k<true><<<AB, 256, 0, stream>>>(rowptr, ecol, el, er, Hp, Hagg, N);

    // ---- layer 2 ----
    gemm_mfma_k<256><<<dim3(MB, 4), 256, 0, stream>>>((const unsigned short*)Hagg, W2b, Hp, N, 256);
    attn_k<<<N, 256, 0, stream>>>(Hp, al2, ar2, flag, el, er, 8, 32);
    aggr_hw_k<true><<<AB, 256, 0, stream>>>(rowptr, ecol, el, er, Hp, Hagg, N);

    // ---- output layer ----
    gemm_mfma_k<256><<<dim3(MB, 1), 256, 0, stream>>>((const unsigned short*)Hagg, Wob, Hp, N, 40);
    attn_k<<<N, 64, 0, stream>>>(Hp, alo, aro, flag, el, er, 1, 40);
    aggr_k<1, 40, 64, false, float><<<N, 64, 0, stream>>>(rowptr, ecol, el, er, Hp, Fout);
    logsm_k<<<N, 64, 0, stream>>>(Fout, d_out, flag);
}

// Round 7
// 645.617 us; speedup vs baseline: 2.6240x; 1.0811x over previous
//
#include <hip/hip_runtime.h>
#include <hip/hip_bf16.h>

#define N_NODES 50000
#define N_EDGES 800000

typedef __bf16 bf16x8 __attribute__((ext_vector_type(8)));
typedef float f32x4 __attribute__((ext_vector_type(4)));

__device__ __forceinline__ float loadF(const void* p, size_t i, bool isbf) {
    return isbf ? __bfloat162float(((const __hip_bfloat16*)p)[i]) : ((const float*)p)[i];
}
__device__ __forceinline__ float bfbits2f(unsigned short u) {
    return __uint_as_float(((unsigned)u) << 16);
}

// ---------- dtype detect ----------
__global__ void detect_k(const unsigned short* __restrict__ xw, int* __restrict__ flag) {
    int t = threadIdx.x;
    int cnt = 0;
    for (int i = t; i < 512; i += 64) {
        unsigned e = (xw[2 * i] >> 7) & 0xFFu;
        if (e >= 117u && e <= 134u) cnt++;
    }
    for (int off = 32; off; off >>= 1) cnt += __shfl_down(cnt, off, 64);
    if (t == 0) *flag = (cnt >= 256) ? 1 : 0;
}

// ---------- one kernel converts x, W1, W2, Wo to bf16 ----------
__global__ void cvt_all_k(const void* __restrict__ x, const void* __restrict__ W1,
                          const void* __restrict__ W2, const void* __restrict__ Wo,
                          unsigned short* __restrict__ Xb, unsigned short* __restrict__ W1b,
                          unsigned short* __restrict__ W2b, unsigned short* __restrict__ Wob,
                          const int* __restrict__ flag) {
    int i = blockIdx.x * blockDim.x + threadIdx.x;
    const void* src; unsigned short* dst; int off;
    if (i < 800000)      { src = x;  dst = Xb;  off = i; }
    else if (i < 804096) { src = W1; dst = W1b; off = i - 800000; }
    else if (i < 812288) { src = W2; dst = W2b; off = i - 804096; }
    else if (i < 813568) { src = Wo; dst = Wob; off = i - 812288; }
    else return;
    if (*flag) {
        ((uint4*)dst)[off] = ((const uint4*)src)[off];
    } else {
        const float* f = (const float*)src + (size_t)off * 8;
        unsigned short r[8];
        for (int j = 0; j < 8; ++j) {
            __hip_bfloat16 h = __float2bfloat16(f[j]);
            r[j] = *(unsigned short*)&h;
        }
        *(uint4*)(dst + (size_t)off * 8) = *(uint4*)r;
    }
}

// ---------- CSR build ----------
__global__ void hist_k(const int* __restrict__ dst, int* __restrict__ cnt, int E) {
    int e = blockIdx.x * blockDim.x + threadIdx.x;
    if (e < E) atomicAdd(&cnt[dst[e]], 1);
}

// single-block scan: 1024 threads, chunked serial + LDS scan
__global__ void scan_k(const int* __restrict__ deg, int* __restrict__ rowptr, int N, int E) {
    __shared__ int s[1024];
    int t = threadIdx.x;
    const int CH = (N + 1023) / 1024;
    int base = t * CH;
    int local = 0;
    for (int i = 0; i < CH; ++i) {
        int g = base + i;
        if (g < N) local += deg[g];
    }
    s[t] = local;
    __syncthreads();
    int v = local;
    for (int off = 1; off < 1024; off <<= 1) {
        int x = (t >= off) ? s[t - off] : 0;
        __syncthreads();
        s[t] += x;
        __syncthreads();
    }
    int run = s[t] - v;   // exclusive prefix of this chunk
    for (int i = 0; i < CH; ++i) {
        int g = base + i;
        if (g < N) { rowptr[g] = run; run += deg[g]; }
    }
    if (t == 0) rowptr[N] = E;
}

__global__ void scatter_k(const int* __restrict__ src, const int* __restrict__ dst,
                          const int* __restrict__ rowptr, int* __restrict__ cursor,
                          int* __restrict__ ecol, int E) {
    int e = blockIdx.x * blockDim.x + threadIdx.x;
    if (e >= E) return;
    int d = dst[e];
    int r = atomicSub(&cursor[d], 1);
    ecol[rowptr[d] + r - 1] = src[e];
}

// ---------- MFMA GEMM + fused attention coefficients ----------
// AMODE 0: H=8,F=32 — head = col0/32 + (wave&1), direct store to el/er[N*8]
// AMODE 1: H=1 (Nfull=40) — atomicAdd partials into el/er[N]
template <int K_, int AMODE>
__global__ __launch_bounds__(256)
void gemm_attn_k(const unsigned short* __restrict__ A, const unsigned short* __restrict__ B,
                 __hip_bfloat16* __restrict__ C, const void* __restrict__ al,
                 const void* __restrict__ ar, const int* __restrict__ flag,
                 float* __restrict__ el, float* __restrict__ er, int M, int Nfull) {
    constexpr int BKC = 128;
    constexpr int LDA = BKC + 8;
    __shared__ unsigned short As[128 * LDA];
    __shared__ unsigned short Bs[64 * LDA];
    int t = threadIdx.x;
    int row0 = blockIdx.x * 128;
    int col0 = blockIdx.y * 64;

    int wave = t >> 6, lane = t & 63;
    int wr = (wave >> 1) * 64, wc = (wave & 1) * 32;
    int m16 = lane & 15, quad = lane >> 4;

    f32x4 acc[4][2] = {};

    for (int k0 = 0; k0 < K_; k0 += BKC) {
        for (int i = t; i < 128 * BKC / 8; i += 256) {
            int r = i / (BKC / 8);
            int c = (i % (BKC / 8)) * 8;
            int gr = row0 + r;
            uint4 v = make_uint4(0u, 0u, 0u, 0u);
            if (gr < M) v = *(const uint4*)&A[(size_t)gr * K_ + k0 + c];
            *(uint4*)&As[r * LDA + c] = v;
        }
        for (int i = t; i < 64 * BKC; i += 256) {
            int n = i % 64;
            int k = i / 64;
            unsigned short v = 0;
            if (col0 + n < Nfull) v = B[(size_t)(k0 + k) * Nfull + col0 + n];
            Bs[n * LDA + k] = v;
        }
        __syncthreads();

        for (int kk = 0; kk < BKC; kk += 32) {
            bf16x8 a[4], b[2];
            for (int mt = 0; mt < 4; ++mt)
                a[mt] = *(const bf16x8*)&As[(wr + mt * 16 + m16) * LDA + kk + quad * 8];
            for (int nt = 0; nt < 2; ++nt)
                b[nt] = *(const bf16x8*)&Bs[(wc + nt * 16 + m16) * LDA + kk + quad * 8];
            for (int mt = 0; mt < 4; ++mt)
                for (int nt = 0; nt < 2; ++nt)
                    acc[mt][nt] = __builtin_amdgcn_mfma_f32_16x16x32_bf16(
                        a[mt], b[nt], acc[mt][nt], 0, 0, 0);
        }
        __syncthreads();
    }

    // C store
    for (int mt = 0; mt < 4; ++mt)
        for (int nt = 0; nt < 2; ++nt)
            for (int r = 0; r < 4; ++r) {
                int gr = row0 + wr + mt * 16 + quad * 4 + r;
                int gc = col0 + wc + nt * 16 + m16;
                if (gr < M && gc < Nfull)
                    C[(size_t)gr * Nfull + gc] = __float2bfloat16(acc[mt][nt][r]);
            }

    // fused attention coefficients
    bool bf = (*flag != 0);
    float alc[2], arc[2];
    for (int nt = 0; nt < 2; ++nt) {
        int gc = col0 + wc + nt * 16 + m16;
        bool ok = gc < Nfull;
        alc[nt] = ok ? loadF(al, gc, bf) : 0.f;
        arc[nt] = ok ? loadF(ar, gc, bf) : 0.f;
    }
    for (int mt = 0; mt < 4; ++mt)
        for (int r = 0; r < 4; ++r) {
            float pl = acc[mt][0][r] * alc[0] + acc[mt][1][r] * alc[1];
            float pr = acc[mt][0][r] * arc[0] + acc[mt][1][r] * arc[1];
            for (int off = 1; off < 16; off <<= 1) {
                pl += __shfl_xor(pl, off, 64);
                pr += __shfl_xor(pr, off, 64);
            }
            if (m16 == 0) {
                int gr = row0 + wr + mt * 16 + quad * 4 + r;
                if (gr < M) {
                    if (AMODE == 0) {
                        int hd = col0 / 32 + (wave & 1);
                        el[gr * 8 + hd] = pl;
                        er[gr * 8 + hd] = pr;
                    } else {
                        atomicAdd(&el[gr], pl);
                        atomicAdd(&er[gr], pr);
                    }
                }
            }
        }
}

// ---------- single-pass half-wave aggregation (H=8, F=32) ----------
// 32 lanes/node, 8 nodes/block. out = (sum_i exp(v_i) * h_i) / (sum_i exp(v_i)), ELU.
__global__ __launch_bounds__(256)
void aggr1_k(const int* __restrict__ rowptr, const int* __restrict__ ecol,
             const float* __restrict__ el, const float* __restrict__ er,
             const __hip_bfloat16* __restrict__ Hp, __hip_bfloat16* __restrict__ out, int N) {
    int t = threadIdx.x;
    int hw = t >> 5, l = t & 31;
    int n = blockIdx.x * 8 + hw;
    if (n >= N) return;
    int beg = rowptr[n], deg = rowptr[n + 1] - beg;

    int hh = l >> 2;                       // head of feats [8l, 8l+8)
    float er_hh = er[n * 8 + hh];
    float ss = 0.f;
    float acc[8] = {0.f, 0.f, 0.f, 0.f, 0.f, 0.f, 0.f, 0.f};
    for (int i = 0; i < deg; ++i) {
        int s = ecol[beg + i];
        float v = el[s * 8 + hh] + er_hh;
        v = (v >= 0.f) ? v : 0.2f * v;
        float ex = __expf(v);
        ss += ex;
        uint4 r = *(const uint4*)((const unsigned short*)Hp + (size_t)s * 256 + l * 8);
        unsigned short u[8];
        *(uint4*)u = r;
        for (int j = 0; j < 8; ++j) acc[j] += ex * bfbits2f(u[j]);
    }
    float inv = 1.f / (ss + 1e-16f);
    unsigned short o[8];
    for (int j = 0; j < 8; ++j) {
        float vv = acc[j] * inv;
        vv = (vv > 0.f) ? vv : expm1f(vv);   // ELU
        __hip_bfloat16 hb = __float2bfloat16(vv);
        o[j] = *(unsigned short*)&hb;
    }
    *(uint4*)((unsigned short*)out + (size_t)n * 256 + l * 8) = *(uint4*)o;
}

// ---------- output layer: single-pass aggregation (H=1,F=40) + log_softmax ----------
__global__ __launch_bounds__(64)
void aggr_out_k(const int* __restrict__ rowptr, const int* __restrict__ ecol,
                const float* __restrict__ elo, const float* __restrict__ ero,
                const __hip_bfloat16* __restrict__ Hp40, void* __restrict__ outp,
                const int* __restrict__ flag, int N) {
    int n = blockIdx.x, l = threadIdx.x;
    int beg = rowptr[n], deg = rowptr[n + 1] - beg;
    float ero_n = ero[n];
    float ss = 0.f, acc = 0.f;
    for (int i = 0; i < deg; ++i) {
        int s = ecol[beg + i];
        float v = elo[s] + ero_n;
        v = (v >= 0.f) ? v : 0.2f * v;
        float ex = __expf(v);
        ss += ex;
        if (l < 40) acc += ex * __bfloat162float(Hp40[(size_t)s * 40 + l]);
    }
    float r = acc / (ss + 1e-16f);
    // log_softmax across lanes 0..39
    float v = (l < 40) ? r : -1e30f;
    for (int off = 32; off; off >>= 1) v = fmaxf(v, __shfl_xor(v, off, 64));
    float ex = (l < 40) ? __expf(r - v) : 0.f;
    for (int off = 32; off; off >>= 1) ex += __shfl_xor(ex, off, 64);
    float lse = v + logf(ex);
    if (l < 40) {
        float o = r - lse;
        if (*flag) ((__hip_bfloat16*)outp)[(size_t)n * 40 + l] = __float2bfloat16(o);
        else       ((float*)outp)[(size_t)n * 40 + l] = o;
    }
}

extern "C" void kernel_launch(void* const* d_in, const int* in_sizes, int n_in,
                              void* d_out, int out_size, void* d_ws, size_t ws_size,
                              hipStream_t stream) {
    const int N = N_NODES, E = N_EDGES;
    const void* x   = d_in[0];
    const int* src  = (const int*)d_in[1];
    const int* dst  = (const int*)d_in[2];
    const void* W1  = d_in[3];
    const void* al1 = d_in[4];
    const void* ar1 = d_in[5];
    const void* W2  = d_in[6];
    const void* al2 = d_in[7];
    const void* ar2 = d_in[8];
    const void* Wo  = d_in[9];
    const void* alo = d_in[10];
    const void* aro = d_in[11];

    // workspace (~58.6 MB)
    char* w = (char*)d_ws;
    auto alloc = [&](size_t bytes) { void* p = (void*)w; w += (bytes + 255) & ~(size_t)255; return p; };
    int* flag      = (int*)alloc(4);
    int* rowptr    = (int*)alloc((size_t)(N + 1) * 4);
    // contiguous zero region: cursor | elo | ero
    int* cursor    = (int*)alloc((size_t)N * 4);
    float* elo     = (float*)alloc((size_t)N * 4);
    float* ero     = (float*)alloc((size_t)N * 4);
    int* ecol      = (int*)alloc((size_t)E * 4);
    float* el      = (float*)alloc((size_t)N * 8 * 4);
    float* er      = (float*)alloc((size_t)N * 8 * 4);
    unsigned short* W1b = (unsigned short*)alloc((size_t)128 * 256 * 2);
    unsigned short* W2b = (unsigned short*)alloc((size_t)256 * 256 * 2);
    unsigned short* Wob = (unsigned short*)alloc((size_t)256 * 40 * 2);
    __hip_bfloat16* Hp   = (__hip_bfloat16*)alloc((size_t)N * 256 * 2);
    __hip_bfloat16* Hagg = (__hip_bfloat16*)alloc((size_t)N * 256 * 2);
    unsigned short* Xb = (unsigned short*)Hagg;   // alias: dead after gemm1 reads it

    int EB = (E + 255) / 256;
    int MB = (N + 127) / 128;
    int AB = (N + 7) / 8;

    // 1: dtype flag
    detect_k<<<1, 64, 0, stream>>>((const unsigned short*)x, flag);
    // 2: all bf16 conversions
    cvt_all_k<<<(813568 + 255) / 256, 256, 0, stream>>>(x, W1, W2, Wo, Xb, W1b, W2b, Wob, flag);
    // 3: zero cursor + elo + ero (contiguous)
    hipMemsetAsync(cursor, 0, (size_t)N * 3 * 4, stream);
    // 4-6: CSR build
    hist_k<<<EB, 256, 0, stream>>>(dst, cursor, E);
    scan_k<<<1, 1024, 0, stream>>>(cursor, rowptr, N, E);
    scatter_k<<<EB, 256, 0, stream>>>(src, dst, rowptr, cursor, ecol, E);

    // 7-8: layer 1
    gemm_attn_k<128, 0><<<dim3(MB, 4), 256, 0, stream>>>(Xb, W1b, Hp, al1, ar1, flag, el, er, N, 256);
    aggr1_k<<<AB, 256, 0, stream>>>(rowptr, ecol, el, er, Hp, Hagg, N);

    // 9-10: layer 2
    gemm_attn_k<256, 0><<<dim3(MB, 4), 256, 0, stream>>>((const unsigned short*)Hagg, W2b, Hp, al2, ar2, flag, el, er, N, 256);
    aggr1_k<<<AB, 256, 0, stream>>>(rowptr, ecol, el, er, Hp, Hagg, N);

    // 11-12: output layer (gemm + atomic attn, then fused aggr+log_softmax)
    gemm_attn_k<256, 1><<<dim3(MB, 1), 256, 0, stream>>>((const unsigned short*)Hagg, Wob, Hp, alo, aro, flag, elo, ero, N, 40);
    aggr_out_k<<<N, 64, 0, stream>>>(rowptr, ecol, elo, ero, Hp, d_out, flag, N);
}

// Round 8
// 542.863 us; speedup vs baseline: 3.1206x; 1.1893x over previous
//
#include <hip/hip_runtime.h>
#include <hip/hip_bf16.h>

#define N_NODES 50000
#define N_EDGES 800000

typedef __bf16 bf16x8 __attribute__((ext_vector_type(8)));
typedef float f32x4 __attribute__((ext_vector_type(4)));

__device__ __forceinline__ float loadF(const void* p, size_t i, bool isbf) {
    return isbf ? __bfloat162float(((const __hip_bfloat16*)p)[i]) : ((const float*)p)[i];
}
__device__ __forceinline__ float bfbits2f(unsigned short u) {
    return __uint_as_float(((unsigned)u) << 16);
}

// ---------- dtype detect ----------
__global__ void detect_k(const unsigned short* __restrict__ xw, int* __restrict__ flag) {
    int t = threadIdx.x;
    int cnt = 0;
    for (int i = t; i < 512; i += 64) {
        unsigned e = (xw[2 * i] >> 7) & 0xFFu;
        if (e >= 117u && e <= 134u) cnt++;
    }
    for (int off = 32; off; off >>= 1) cnt += __shfl_down(cnt, off, 64);
    if (t == 0) *flag = (cnt >= 256) ? 1 : 0;
}

// ---------- one kernel converts x, W1, W2, Wo to bf16 ----------
__global__ void cvt_all_k(const void* __restrict__ x, const void* __restrict__ W1,
                          const void* __restrict__ W2, const void* __restrict__ Wo,
                          unsigned short* __restrict__ Xb, unsigned short* __restrict__ W1b,
                          unsigned short* __restrict__ W2b, unsigned short* __restrict__ Wob,
                          const int* __restrict__ flag) {
    int i = blockIdx.x * blockDim.x + threadIdx.x;
    const void* src; unsigned short* dst; int off;
    if (i < 800000)      { src = x;  dst = Xb;  off = i; }
    else if (i < 804096) { src = W1; dst = W1b; off = i - 800000; }
    else if (i < 812288) { src = W2; dst = W2b; off = i - 804096; }
    else if (i < 813568) { src = Wo; dst = Wob; off = i - 812288; }
    else return;
    if (*flag) {
        ((uint4*)dst)[off] = ((const uint4*)src)[off];
    } else {
        const float* f = (const float*)src + (size_t)off * 8;
        unsigned short r[8];
        for (int j = 0; j < 8; ++j) {
            __hip_bfloat16 h = __float2bfloat16(f[j]);
            r[j] = *(unsigned short*)&h;
        }
        *(uint4*)(dst + (size_t)off * 8) = *(uint4*)r;
    }
}

// ---------- CSR build ----------
__global__ void hist_k(const int* __restrict__ dst, int* __restrict__ cnt, int E) {
    int e = blockIdx.x * blockDim.x + threadIdx.x;
    if (e < E) atomicAdd(&cnt[dst[e]], 1);
}

// block-local exclusive scan + block sums (196 blocks x 256 threads)
__global__ void scan1_k(const int* __restrict__ deg, int* __restrict__ rowptr,
                        int* __restrict__ bsum, int N) {
    __shared__ int s[256];
    int t = threadIdx.x, g = blockIdx.x * 256 + t;
    int v = (g < N) ? deg[g] : 0;
    s[t] = v; __syncthreads();
    for (int off = 1; off < 256; off <<= 1) {
        int x = (t >= off) ? s[t - off] : 0;
        __syncthreads();
        s[t] += x;
        __syncthreads();
    }
    if (g < N) rowptr[g] = s[t] - v;
    if (t == 255) bsum[blockIdx.x] = s[255];
}

// each block reduces bsum[0..bid) and adds its offset (folds old scan2+scan3)
__global__ void scan23_k(int* __restrict__ rowptr, const int* __restrict__ bsum, int N, int E) {
    __shared__ int ws[4];
    __shared__ int s_off;
    int bid = blockIdx.x, t = threadIdx.x;
    int wave = t >> 6, lane = t & 63;
    int v = (t < bid) ? bsum[t] : 0;   // bid <= 196 < 256
    for (int off = 32; off; off >>= 1) v += __shfl_down(v, off, 64);
    if (lane == 0) ws[wave] = v;
    __syncthreads();
    if (t == 0) s_off = ws[0] + ws[1] + ws[2] + ws[3];
    __syncthreads();
    int g = bid * 256 + t;
    if (g < N) rowptr[g] += s_off;
    if (g == 0) rowptr[N] = E;
}

__global__ void scatter_k(const int* __restrict__ src, const int* __restrict__ dst,
                          const int* __restrict__ rowptr, int* __restrict__ cursor,
                          int* __restrict__ ecol, int E) {
    int e = blockIdx.x * blockDim.x + threadIdx.x;
    if (e >= E) return;
    int d = dst[e];
    int r = atomicSub(&cursor[d], 1);
    ecol[rowptr[d] + r - 1] = src[e];
}

// ---------- MFMA GEMM + fused attention coefficients ----------
template <int K_, int AMODE>
__global__ __launch_bounds__(256)
void gemm_attn_k(const unsigned short* __restrict__ A, const unsigned short* __restrict__ B,
                 __hip_bfloat16* __restrict__ C, const void* __restrict__ al,
                 const void* __restrict__ ar, const int* __restrict__ flag,
                 float* __restrict__ el, float* __restrict__ er, int M, int Nfull) {
    constexpr int BKC = 128;
    constexpr int LDA = BKC + 8;
    __shared__ unsigned short As[128 * LDA];
    __shared__ unsigned short Bs[64 * LDA];
    int t = threadIdx.x;
    int row0 = blockIdx.x * 128;
    int col0 = blockIdx.y * 64;

    int wave = t >> 6, lane = t & 63;
    int wr = (wave >> 1) * 64, wc = (wave & 1) * 32;
    int m16 = lane & 15, quad = lane >> 4;

    f32x4 acc[4][2] = {};

    for (int k0 = 0; k0 < K_; k0 += BKC) {
        for (int i = t; i < 128 * BKC / 8; i += 256) {
            int r = i / (BKC / 8);
            int c = (i % (BKC / 8)) * 8;
            int gr = row0 + r;
            uint4 v = make_uint4(0u, 0u, 0u, 0u);
            if (gr < M) v = *(const uint4*)&A[(size_t)gr * K_ + k0 + c];
            *(uint4*)&As[r * LDA + c] = v;
        }
        for (int i = t; i < 64 * BKC; i += 256) {
            int n = i % 64;
            int k = i / 64;
            unsigned short v = 0;
            if (col0 + n < Nfull) v = B[(size_t)(k0 + k) * Nfull + col0 + n];
            Bs[n * LDA + k] = v;
        }
        __syncthreads();

        for (int kk = 0; kk < BKC; kk += 32) {
            bf16x8 a[4], b[2];
            for (int mt = 0; mt < 4; ++mt)
                a[mt] = *(const bf16x8*)&As[(wr + mt * 16 + m16) * LDA + kk + quad * 8];
            for (int nt = 0; nt < 2; ++nt)
                b[nt] = *(const bf16x8*)&Bs[(wc + nt * 16 + m16) * LDA + kk + quad * 8];
            for (int mt = 0; mt < 4; ++mt)
                for (int nt = 0; nt < 2; ++nt)
                    acc[mt][nt] = __builtin_amdgcn_mfma_f32_16x16x32_bf16(
                        a[mt], b[nt], acc[mt][nt], 0, 0, 0);
        }
        __syncthreads();
    }

    for (int mt = 0; mt < 4; ++mt)
        for (int nt = 0; nt < 2; ++nt)
            for (int r = 0; r < 4; ++r) {
                int gr = row0 + wr + mt * 16 + quad * 4 + r;
                int gc = col0 + wc + nt * 16 + m16;
                if (gr < M && gc < Nfull)
                    C[(size_t)gr * Nfull + gc] = __float2bfloat16(acc[mt][nt][r]);
            }

    bool bf = (*flag != 0);
    float alc[2], arc[2];
    for (int nt = 0; nt < 2; ++nt) {
        int gc = col0 + wc + nt * 16 + m16;
        bool ok = gc < Nfull;
        alc[nt] = ok ? loadF(al, gc, bf) : 0.f;
        arc[nt] = ok ? loadF(ar, gc, bf) : 0.f;
    }
    for (int mt = 0; mt < 4; ++mt)
        for (int r = 0; r < 4; ++r) {
            float pl = acc[mt][0][r] * alc[0] + acc[mt][1][r] * alc[1];
            float pr = acc[mt][0][r] * arc[0] + acc[mt][1][r] * arc[1];
            for (int off = 1; off < 16; off <<= 1) {
                pl += __shfl_xor(pl, off, 64);
                pr += __shfl_xor(pr, off, 64);
            }
            if (m16 == 0) {
                int gr = row0 + wr + mt * 16 + quad * 4 + r;
                if (gr < M) {
                    if (AMODE == 0) {
                        int hd = col0 / 32 + (wave & 1);
                        el[gr * 8 + hd] = pl;
                        er[gr * 8 + hd] = pr;
                    } else {
                        atomicAdd(&el[gr], pl);
                        atomicAdd(&er[gr], pr);
                    }
                }
            }
        }
}

// ---------- single-pass half-wave aggregation (H=8, F=32), unrolled x2 ----------
__global__ __launch_bounds__(256)
void aggr1_k(const int* __restrict__ rowptr, const int* __restrict__ ecol,
             const float* __restrict__ el, const float* __restrict__ er,
             const __hip_bfloat16* __restrict__ Hp, __hip_bfloat16* __restrict__ out, int N) {
    int t = threadIdx.x;
    int hw = t >> 5, l = t & 31;
    int n = blockIdx.x * 8 + hw;
    if (n >= N) return;
    int beg = rowptr[n], deg = rowptr[n + 1] - beg;

    int hh = l >> 2;
    float er_hh = er[n * 8 + hh];
    float ss = 0.f;
    float acc[8] = {0.f, 0.f, 0.f, 0.f, 0.f, 0.f, 0.f, 0.f};
    const unsigned short* hp = (const unsigned short*)Hp;

    int i = 0;
    for (; i + 2 <= deg; i += 2) {
        int s0 = ecol[beg + i], s1 = ecol[beg + i + 1];
        uint4 r0 = *(const uint4*)(hp + (size_t)s0 * 256 + l * 8);
        uint4 r1 = *(const uint4*)(hp + (size_t)s1 * 256 + l * 8);
        float v0 = el[s0 * 8 + hh] + er_hh;
        float v1 = el[s1 * 8 + hh] + er_hh;
        v0 = (v0 >= 0.f) ? v0 : 0.2f * v0;
        v1 = (v1 >= 0.f) ? v1 : 0.2f * v1;
        float e0 = __expf(v0), e1 = __expf(v1);
        ss += e0 + e1;
        unsigned short u0[8], u1[8];
        *(uint4*)u0 = r0;
        *(uint4*)u1 = r1;
        for (int j = 0; j < 8; ++j) acc[j] += e0 * bfbits2f(u0[j]) + e1 * bfbits2f(u1[j]);
    }
    if (i < deg) {
        int s0 = ecol[beg + i];
        uint4 r0 = *(const uint4*)(hp + (size_t)s0 * 256 + l * 8);
        float v0 = el[s0 * 8 + hh] + er_hh;
        v0 = (v0 >= 0.f) ? v0 : 0.2f * v0;
        float e0 = __expf(v0);
        ss += e0;
        unsigned short u0[8];
        *(uint4*)u0 = r0;
        for (int j = 0; j < 8; ++j) acc[j] += e0 * bfbits2f(u0[j]);
    }

    float inv = 1.f / (ss + 1e-16f);
    unsigned short o[8];
    for (int j = 0; j < 8; ++j) {
        float vv = acc[j] * inv;
        vv = (vv > 0.f) ? vv : expm1f(vv);   // ELU
        __hip_bfloat16 hb = __float2bfloat16(vv);
        o[j] = *(unsigned short*)&hb;
    }
    *(uint4*)((unsigned short*)out + (size_t)n * 256 + l * 8) = *(uint4*)o;
}

// ---------- output layer: single-pass aggregation (H=1,F=40) + log_softmax ----------
__global__ __launch_bounds__(64)
void aggr_out_k(const int* __restrict__ rowptr, const int* __restrict__ ecol,
                const float* __restrict__ elo, const float* __restrict__ ero,
                const __hip_bfloat16* __restrict__ Hp40, void* __restrict__ outp,
                const int* __restrict__ flag, int N) {
    int n = blockIdx.x, l = threadIdx.x;
    int beg = rowptr[n], deg = rowptr[n + 1] - beg;
    float ero_n = ero[n];
    float ss = 0.f, acc = 0.f;
    for (int i = 0; i < deg; ++i) {
        int s = ecol[beg + i];
        float v = elo[s] + ero_n;
        v = (v >= 0.f) ? v : 0.2f * v;
        float ex = __expf(v);
        ss += ex;
        if (l < 40) acc += ex * __bfloat162float(Hp40[(size_t)s * 40 + l]);
    }
    float r = acc / (ss + 1e-16f);
    float v = (l < 40) ? r : -1e30f;
    for (int off = 32; off; off >>= 1) v = fmaxf(v, __shfl_xor(v, off, 64));
    float ex = (l < 40) ? __expf(r - v) : 0.f;
    for (int off = 32; off; off >>= 1) ex += __shfl_xor(ex, off, 64);
    float lse = v + logf(ex);
    if (l < 40) {
        float o = r - lse;
        if (*flag) ((__hip_bfloat16*)outp)[(size_t)n * 40 + l] = __float2bfloat16(o);
        else       ((float*)outp)[(size_t)n * 40 + l] = o;
    }
}

extern "C" void kernel_launch(void* const* d_in, const int* in_sizes, int n_in,
                              void* d_out, int out_size, void* d_ws, size_t ws_size,
                              hipStream_t stream) {
    const int N = N_NODES, E = N_EDGES;
    const void* x   = d_in[0];
    const int* src  = (const int*)d_in[1];
    const int* dst  = (const int*)d_in[2];
    const void* W1  = d_in[3];
    const void* al1 = d_in[4];
    const void* ar1 = d_in[5];
    const void* W2  = d_in[6];
    const void* al2 = d_in[7];
    const void* ar2 = d_in[8];
    const void* Wo  = d_in[9];
    const void* alo = d_in[10];
    const void* aro = d_in[11];

    // workspace (~58.6 MB)
    char* w = (char*)d_ws;
    auto alloc = [&](size_t bytes) { void* p = (void*)w; w += (bytes + 255) & ~(size_t)255; return p; };
    int* flag      = (int*)alloc(4);
    int* rowptr    = (int*)alloc((size_t)(N + 1) * 4);
    int* cursor    = (int*)alloc((size_t)N * 4);
    float* elo     = (float*)alloc((size_t)N * 4);
    float* ero     = (float*)alloc((size_t)N * 4);
    int* bsum      = (int*)alloc(256 * 4);
    int* ecol      = (int*)alloc((size_t)E * 4);
    float* el      = (float*)alloc((size_t)N * 8 * 4);
    float* er      = (float*)alloc((size_t)N * 8 * 4);
    unsigned short* W1b = (unsigned short*)alloc((size_t)128 * 256 * 2);
    unsigned short* W2b = (unsigned short*)alloc((size_t)256 * 256 * 2);
    unsigned short* Wob = (unsigned short*)alloc((size_t)256 * 40 * 2);
    __hip_bfloat16* Hp   = (__hip_bfloat16*)alloc((size_t)N * 256 * 2);
    __hip_bfloat16* Hagg = (__hip_bfloat16*)alloc((size_t)N * 256 * 2);
    unsigned short* Xb = (unsigned short*)Hagg;

    int EB = (E + 255) / 256;
    int NB = (N + 255) / 256;
    int MB = (N + 127) / 128;
    int AB = (N + 7) / 8;

    detect_k<<<1, 64, 0, stream>>>((const unsigned short*)x, flag);
    cvt_all_k<<<(813568 + 255) / 256, 256, 0, stream>>>(x, W1, W2, Wo, Xb, W1b, W2b, Wob, flag);
    hipMemsetAsync(cursor, 0, (size_t)N * 3 * 4, stream);  // cursor + elo + ero
    hist_k<<<EB, 256, 0, stream>>>(dst, cursor, E);
    scan1_k<<<NB, 256, 0, stream>>>(cursor, rowptr, bsum, N);
    scan23_k<<<NB, 256, 0, stream>>>(rowptr, bsum, N, E);
    scatter_k<<<EB, 256, 0, stream>>>(src, dst, rowptr, cursor, ecol, E);

    // layer 1
    gemm_attn_k<128, 0><<<dim3(MB, 4), 256, 0, stream>>>(Xb, W1b, Hp, al1, ar1, flag, el, er, N, 256);
    aggr1_k<<<AB, 256, 0, stream>>>(rowptr, ecol, el, er, Hp, Hagg, N);

    // layer 2
    gemm_attn_k<256, 0><<<dim3(MB, 4), 256, 0, stream>>>((const unsigned short*)Hagg, W2b, Hp, al2, ar2, flag, el, er, N, 256);
    aggr1_k<<<AB, 256, 0, stream>>>(rowptr, ecol, el, er, Hp, Hagg, N);

    // output layer
    gemm_attn_k<256, 1><<<dim3(MB, 1), 256, 0, stream>>>((const unsigned short*)Hagg, Wob, Hp, alo, aro, flag, elo, ero, N, 40);
    aggr_out_k<<<N, 64, 0, stream>>>(rowptr, ecol, elo, ero, Hp, d_out, flag, N);
}

// Round 9
// 473.108 us; speedup vs baseline: 3.5807x; 1.1474x over previous
//
#include <hip/hip_runtime.h>
#include <hip/hip_bf16.h>

#define N_NODES 50000
#define N_EDGES 800000

typedef __bf16 bf16x8 __attribute__((ext_vector_type(8)));
typedef float f32x4 __attribute__((ext_vector_type(4)));

__device__ __forceinline__ float loadF(const void* p, size_t i, bool isbf) {
    return isbf ? __bfloat162float(((const __hip_bfloat16*)p)[i]) : ((const float*)p)[i];
}
__device__ __forceinline__ float bfbits2f(unsigned short u) {
    return __uint_as_float(((unsigned)u) << 16);
}
__device__ __forceinline__ unsigned short f2bfbits(float f) {
    __hip_bfloat16 h = __float2bfloat16(f);
    return *(unsigned short*)&h;
}

// ---------- dtype detect ----------
__global__ void detect_k(const unsigned short* __restrict__ xw, int* __restrict__ flag) {
    int t = threadIdx.x;
    int cnt = 0;
    for (int i = t; i < 512; i += 64) {
        unsigned e = (xw[2 * i] >> 7) & 0xFFu;
        if (e >= 117u && e <= 134u) cnt++;
    }
    for (int off = 32; off; off >>= 1) cnt += __shfl_down(cnt, off, 64);
    if (t == 0) *flag = (cnt >= 256) ? 1 : 0;
}

// ---------- convert x to bf16 row-major + swizzle W1/W2/Wo to fragment-major ----------
// Wf layout: unit u = (s*Npad + n)*4 + quad holds 8 shorts: W[s*32+quad*8+j][n]
__global__ void cvt_all_k(const void* __restrict__ x, const void* __restrict__ W1,
                          const void* __restrict__ W2, const void* __restrict__ Wo,
                          unsigned short* __restrict__ Xb, unsigned short* __restrict__ W1f,
                          unsigned short* __restrict__ W2f, unsigned short* __restrict__ Wof,
                          const int* __restrict__ flag) {
    int i = blockIdx.x * blockDim.x + threadIdx.x;
    bool bf = (*flag != 0);
    if (i < 800000) {                       // x: 6.4M elems as uint4-of-8
        if (bf) {
            ((uint4*)Xb)[i] = ((const uint4*)x)[i];
        } else {
            const float* f = (const float*)x + (size_t)i * 8;
            unsigned short r[8];
            for (int j = 0; j < 8; ++j) r[j] = f2bfbits(f[j]);
            *(uint4*)(Xb + (size_t)i * 8) = *(uint4*)r;
        }
        return;
    }
    int u = i - 800000;
    const void* W; unsigned short* dst; int Nf, Npad, s, rem;
    if (u < 4096)        { W = W1; dst = W1f; Nf = 256; Npad = 256; s = u / 1024; rem = u % 1024; }
    else if (u < 12288)  { u -= 4096;  W = W2; dst = W2f; Nf = 256; Npad = 256; s = u / 1024; rem = u % 1024; }
    else if (u < 14336)  { u -= 12288; W = Wo; dst = Wof; Nf = 40;  Npad = 64;  s = u / 256;  rem = u % 256; }
    else return;
    int n = rem >> 2, quad = rem & 3;
    unsigned short r[8];
    for (int j = 0; j < 8; ++j) {
        int k = s * 32 + quad * 8 + j;
        r[j] = (n < Nf) ? f2bfbits(loadF(W, (size_t)k * Nf + n, bf)) : (unsigned short)0;
    }
    int uo = (s * Npad + n) * 4 + quad;
    *(uint4*)(dst + (size_t)uo * 8) = *(uint4*)r;
}

// ---------- CSR build ----------
__global__ void hist_k(const int* __restrict__ dst, int* __restrict__ cnt, int E) {
    int e = blockIdx.x * blockDim.x + threadIdx.x;
    if (e < E) atomicAdd(&cnt[dst[e]], 1);
}

__global__ void scan1_k(const int* __restrict__ deg, int* __restrict__ rowptr,
                        int* __restrict__ bsum, int N) {
    __shared__ int s[256];
    int t = threadIdx.x, g = blockIdx.x * 256 + t;
    int v = (g < N) ? deg[g] : 0;
    s[t] = v; __syncthreads();
    for (int off = 1; off < 256; off <<= 1) {
        int x = (t >= off) ? s[t - off] : 0;
        __syncthreads();
        s[t] += x;
        __syncthreads();
    }
    if (g < N) rowptr[g] = s[t] - v;
    if (t == 255) bsum[blockIdx.x] = s[255];
}

__global__ void scan23_k(int* __restrict__ rowptr, const int* __restrict__ bsum, int N, int E) {
    __shared__ int ws[4];
    __shared__ int s_off;
    int bid = blockIdx.x, t = threadIdx.x;
    int wave = t >> 6, lane = t & 63;
    int v = (t < bid) ? bsum[t] : 0;
    for (int off = 32; off; off >>= 1) v += __shfl_down(v, off, 64);
    if (lane == 0) ws[wave] = v;
    __syncthreads();
    if (t == 0) s_off = ws[0] + ws[1] + ws[2] + ws[3];
    __syncthreads();
    int g = bid * 256 + t;
    if (g < N) rowptr[g] += s_off;
    if (g == 0) rowptr[N] = E;
}

__global__ void scatter_k(const int* __restrict__ src, const int* __restrict__ dst,
                          const int* __restrict__ rowptr, int* __restrict__ cursor,
                          int* __restrict__ ecol, int E) {
    int e = blockIdx.x * blockDim.x + threadIdx.x;
    if (e >= E) return;
    int d = dst[e];
    int r = atomicSub(&cursor[d], 1);
    ecol[rowptr[d] + r - 1] = src[e];
}

// ---------- LDS-free MFMA GEMM + fused attention coefficients ----------
// A row-major [M,K_]: A-fragments are contiguous 16B chunks. Wf fragment-major.
// AMODE 0: H=8 heads (Nfull=256) direct store; AMODE 1: H=1 atomicAdd partials.
template <int K_, int AMODE>
__global__ __launch_bounds__(256)
void gemm_attn_k(const unsigned short* __restrict__ A, const unsigned short* __restrict__ Wf,
                 __hip_bfloat16* __restrict__ C, const void* __restrict__ al,
                 const void* __restrict__ ar, const int* __restrict__ flag,
                 float* __restrict__ el, float* __restrict__ er, int M, int Nfull, int Npad) {
    int t = threadIdx.x;
    int row0 = blockIdx.x * 128, col0 = blockIdx.y * 64;
    int wave = t >> 6, lane = t & 63;
    int wr = (wave >> 1) * 64, wc = (wave & 1) * 32;
    int m16 = lane & 15, quad = lane >> 4;

    const unsigned short* arow[4];
    for (int mt = 0; mt < 4; ++mt) {
        int gr = row0 + wr + mt * 16 + m16;
        int grc = (gr < M) ? gr : (M - 1);          // clamp; OOB rows discarded at store
        arow[mt] = A + (size_t)grc * K_ + quad * 8;
    }
    const unsigned short* bbase[2];
    for (int nt = 0; nt < 2; ++nt) {
        int gc = col0 + wc + nt * 16 + m16;         // < Npad (padded)
        bbase[nt] = Wf + ((size_t)(gc * 4 + quad) << 3);
    }

    f32x4 acc[4][2] = {};
#pragma unroll
    for (int s = 0; s < K_ / 32; ++s) {
        bf16x8 a[4], b[2];
        for (int mt = 0; mt < 4; ++mt)
            a[mt] = *(const bf16x8*)(arow[mt] + s * 32);
        for (int nt = 0; nt < 2; ++nt)
            b[nt] = *(const bf16x8*)(bbase[nt] + (size_t)s * Npad * 32);
        for (int mt = 0; mt < 4; ++mt)
            for (int nt = 0; nt < 2; ++nt)
                acc[mt][nt] = __builtin_amdgcn_mfma_f32_16x16x32_bf16(
                    a[mt], b[nt], acc[mt][nt], 0, 0, 0);
    }

    // C store (D layout: row = quad*4+r, col = m16)
    for (int mt = 0; mt < 4; ++mt)
        for (int nt = 0; nt < 2; ++nt)
            for (int r = 0; r < 4; ++r) {
                int gr = row0 + wr + mt * 16 + quad * 4 + r;
                int gc = col0 + wc + nt * 16 + m16;
                if (gr < M && gc < Nfull)
                    C[(size_t)gr * Nfull + gc] = __float2bfloat16(acc[mt][nt][r]);
            }

    // fused attention coefficients
    bool bf = (*flag != 0);
    float alc[2], arc[2];
    for (int nt = 0; nt < 2; ++nt) {
        int gc = col0 + wc + nt * 16 + m16;
        bool ok = gc < Nfull;
        alc[nt] = ok ? loadF(al, gc, bf) : 0.f;
        arc[nt] = ok ? loadF(ar, gc, bf) : 0.f;
    }
    for (int mt = 0; mt < 4; ++mt)
        for (int r = 0; r < 4; ++r) {
            float pl = acc[mt][0][r] * alc[0] + acc[mt][1][r] * alc[1];
            float pr = acc[mt][0][r] * arc[0] + acc[mt][1][r] * arc[1];
            for (int off = 1; off < 16; off <<= 1) {
                pl += __shfl_xor(pl, off, 64);
                pr += __shfl_xor(pr, off, 64);
            }
            if (m16 == 0) {
                int gr = row0 + wr + mt * 16 + quad * 4 + r;
                if (gr < M) {
                    if (AMODE == 0) {
                        int hd = col0 / 32 + (wave & 1);
                        el[gr * 8 + hd] = pl;
                        er[gr * 8 + hd] = pr;
                    } else {
                        atomicAdd(&el[gr], pl);
                        atomicAdd(&er[gr], pr);
                    }
                }
            }
        }
}

// ---------- single-pass half-wave aggregation (H=8, F=32), unrolled x2 ----------
__global__ __launch_bounds__(256)
void aggr1_k(const int* __restrict__ rowptr, const int* __restrict__ ecol,
             const float* __restrict__ el, const float* __restrict__ er,
             const __hip_bfloat16* __restrict__ Hp, __hip_bfloat16* __restrict__ out, int N) {
    int t = threadIdx.x;
    int hw = t >> 5, l = t & 31;
    int n = blockIdx.x * 8 + hw;
    if (n >= N) return;
    int beg = rowptr[n], deg = rowptr[n + 1] - beg;

    int hh = l >> 2;
    float er_hh = er[n * 8 + hh];
    float ss = 0.f;
    float acc[8] = {0.f, 0.f, 0.f, 0.f, 0.f, 0.f, 0.f, 0.f};
    const unsigned short* hp = (const unsigned short*)Hp;

    int i = 0;
    for (; i + 2 <= deg; i += 2) {
        int s0 = ecol[beg + i], s1 = ecol[beg + i + 1];
        uint4 r0 = *(const uint4*)(hp + (size_t)s0 * 256 + l * 8);
        uint4 r1 = *(const uint4*)(hp + (size_t)s1 * 256 + l * 8);
        float v0 = el[s0 * 8 + hh] + er_hh;
        float v1 = el[s1 * 8 + hh] + er_hh;
        v0 = (v0 >= 0.f) ? v0 : 0.2f * v0;
        v1 = (v1 >= 0.f) ? v1 : 0.2f * v1;
        float e0 = __expf(v0), e1 = __expf(v1);
        ss += e0 + e1;
        unsigned short u0[8], u1[8];
        *(uint4*)u0 = r0;
        *(uint4*)u1 = r1;
        for (int j = 0; j < 8; ++j) acc[j] += e0 * bfbits2f(u0[j]) + e1 * bfbits2f(u1[j]);
    }
    if (i < deg) {
        int s0 = ecol[beg + i];
        uint4 r0 = *(const uint4*)(hp + (size_t)s0 * 256 + l * 8);
        float v0 = el[s0 * 8 + hh] + er_hh;
        v0 = (v0 >= 0.f) ? v0 : 0.2f * v0;
        float e0 = __expf(v0);
        ss += e0;
        unsigned short u0[8];
        *(uint4*)u0 = r0;
        for (int j = 0; j < 8; ++j) acc[j] += e0 * bfbits2f(u0[j]);
    }

    float inv = 1.f / (ss + 1e-16f);
    unsigned short o[8];
    for (int j = 0; j < 8; ++j) {
        float vv = acc[j] * inv;
        vv = (vv > 0.f) ? vv : expm1f(vv);   // ELU
        o[j] = f2bfbits(vv);
    }
    *(uint4*)((unsigned short*)out + (size_t)n * 256 + l * 8) = *(uint4*)o;
}

// ---------- output layer: single-pass aggregation (H=1,F=40) + log_softmax ----------
__global__ __launch_bounds__(64)
void aggr_out_k(const int* __restrict__ rowptr, const int* __restrict__ ecol,
                const float* __restrict__ elo, const float* __restrict__ ero,
                const __hip_bfloat16* __restrict__ Hp40, void* __restrict__ outp,
                const int* __restrict__ flag, int N) {
    int n = blockIdx.x, l = threadIdx.x;
    int beg = rowptr[n], deg = rowptr[n + 1] - beg;
    float ero_n = ero[n];
    float ss = 0.f, acc = 0.f;
    for (int i = 0; i < deg; ++i) {
        int s = ecol[beg + i];
        float v = elo[s] + ero_n;
        v = (v >= 0.f) ? v : 0.2f * v;
        float ex = __expf(v);
        ss += ex;
        if (l < 40) acc += ex * __bfloat162float(Hp40[(size_t)s * 40 + l]);
    }
    float r = acc / (ss + 1e-16f);
    float v = (l < 40) ? r : -1e30f;
    for (int off = 32; off; off >>= 1) v = fmaxf(v, __shfl_xor(v, off, 64));
    float ex = (l < 40) ? __expf(r - v) : 0.f;
    for (int off = 32; off; off >>= 1) ex += __shfl_xor(ex, off, 64);
    float lse = v + logf(ex);
    if (l < 40) {
        float o = r - lse;
        if (*flag) ((__hip_bfloat16*)outp)[(size_t)n * 40 + l] = __float2bfloat16(o);
        else       ((float*)outp)[(size_t)n * 40 + l] = o;
    }
}

extern "C" void kernel_launch(void* const* d_in, const int* in_sizes, int n_in,
                              void* d_out, int out_size, void* d_ws, size_t ws_size,
                              hipStream_t stream) {
    const int N = N_NODES, E = N_EDGES;
    const void* x   = d_in[0];
    const int* src  = (const int*)d_in[1];
    const int* dst  = (const int*)d_in[2];
    const void* W1  = d_in[3];
    const void* al1 = d_in[4];
    const void* ar1 = d_in[5];
    const void* W2  = d_in[6];
    const void* al2 = d_in[7];
    const void* ar2 = d_in[8];
    const void* Wo  = d_in[9];
    const void* alo = d_in[10];
    const void* aro = d_in[11];

    // workspace (~58.6 MB)
    char* w = (char*)d_ws;
    auto alloc = [&](size_t bytes) { void* p = (void*)w; w += (bytes + 255) & ~(size_t)255; return p; };
    int* flag      = (int*)alloc(4);
    int* rowptr    = (int*)alloc((size_t)(N + 1) * 4);
    int* cursor    = (int*)alloc((size_t)N * 4);
    float* elo     = (float*)alloc((size_t)N * 4);
    float* ero     = (float*)alloc((size_t)N * 4);
    int* bsum      = (int*)alloc(256 * 4);
    int* ecol      = (int*)alloc((size_t)E * 4);
    float* el      = (float*)alloc((size_t)N * 8 * 4);
    float* er      = (float*)alloc((size_t)N * 8 * 4);
    unsigned short* W1f = (unsigned short*)alloc((size_t)128 * 256 * 2);
    unsigned short* W2f = (unsigned short*)alloc((size_t)256 * 256 * 2);
    unsigned short* Wof = (unsigned short*)alloc((size_t)256 * 64 * 2);
    __hip_bfloat16* Hp   = (__hip_bfloat16*)alloc((size_t)N * 256 * 2);
    __hip_bfloat16* Hagg = (__hip_bfloat16*)alloc((size_t)N * 256 * 2);
    unsigned short* Xb = (unsigned short*)Hagg;   // alias: dead after layer-1 gemm

    int EB = (E + 255) / 256;
    int NB = (N + 255) / 256;
    int MB = (N + 127) / 128;
    int AB = (N + 7) / 8;

    detect_k<<<1, 64, 0, stream>>>((const unsigned short*)x, flag);
    cvt_all_k<<<(814336 + 255) / 256, 256, 0, stream>>>(x, W1, W2, Wo, Xb, W1f, W2f, Wof, flag);
    hipMemsetAsync(cursor, 0, (size_t)N * 3 * 4, stream);  // cursor + elo + ero
    hist_k<<<EB, 256, 0, stream>>>(dst, cursor, E);
    scan1_k<<<NB, 256, 0, stream>>>(cursor, rowptr, bsum, N);
    scan23_k<<<NB, 256, 0, stream>>>(rowptr, bsum, N, E);
    scatter_k<<<EB, 256, 0, stream>>>(src, dst, rowptr, cursor, ecol, E);

    // layer 1
    gemm_attn_k<128, 0><<<dim3(MB, 4), 256, 0, stream>>>(Xb, W1f, Hp, al1, ar1, flag, el, er, N, 256, 256);
    aggr1_k<<<AB, 256, 0, stream>>>(rowptr, ecol, el, er, Hp, Hagg, N);

    // layer 2
    gemm_attn_k<256, 0><<<dim3(MB, 4), 256, 0, stream>>>((const unsigned short*)Hagg, W2f, Hp, al2, ar2, flag, el, er, N, 256, 256);
    aggr1_k<<<AB, 256, 0, stream>>>(rowptr, ecol, el, er, Hp, Hagg, N);

    // output layer
    gemm_attn_k<256, 1><<<dim3(MB, 1), 256, 0, stream>>>((const unsigned short*)Hagg, Wof, Hp, alo, aro, flag, elo, ero, N, 40, 64);
    aggr_out_k<<<N, 64, 0, stream>>>(rowptr, ecol, elo, ero, Hp, d_out, flag, N);
}

// Round 10
// 436.075 us; speedup vs baseline: 3.8848x; 1.0849x over previous
//
#include <hip/hip_runtime.h>
#include <hip/hip_bf16.h>

#define N_NODES 50000
#define N_EDGES 800000

typedef __bf16 bf16x8 __attribute__((ext_vector_type(8)));
typedef float f32x4 __attribute__((ext_vector_type(4)));

__device__ __forceinline__ float loadF(const void* p, size_t i, bool isbf) {
    return isbf ? __bfloat162float(((const __hip_bfloat16*)p)[i]) : ((const float*)p)[i];
}
__device__ __forceinline__ float bfbits2f(unsigned short u) {
    return __uint_as_float(((unsigned)u) << 16);
}
__device__ __forceinline__ unsigned short f2bfbits(float f) {
    __hip_bfloat16 h = __float2bfloat16(f);
    return *(unsigned short*)&h;
}

// ---------- dtype detect ----------
__global__ void detect_k(const unsigned short* __restrict__ xw, int* __restrict__ flag) {
    int t = threadIdx.x;
    int cnt = 0;
    for (int i = t; i < 512; i += 64) {
        unsigned e = (xw[2 * i] >> 7) & 0xFFu;
        if (e >= 117u && e <= 134u) cnt++;
    }
    for (int off = 32; off; off >>= 1) cnt += __shfl_down(cnt, off, 64);
    if (t == 0) *flag = (cnt >= 256) ? 1 : 0;
}

// ---------- convert x to bf16 row-major + swizzle W1/W2/Wo to fragment-major ----------
// Wf layout: unit u = (s*Npad + n)*4 + quad holds 8 shorts: W[s*32+quad*8+j][n]
__global__ void cvt_all_k(const void* __restrict__ x, const void* __restrict__ W1,
                          const void* __restrict__ W2, const void* __restrict__ Wo,
                          unsigned short* __restrict__ Xb, unsigned short* __restrict__ W1f,
                          unsigned short* __restrict__ W2f, unsigned short* __restrict__ Wof,
                          const int* __restrict__ flag) {
    int i = blockIdx.x * blockDim.x + threadIdx.x;
    bool bf = (*flag != 0);
    if (i < 800000) {
        if (bf) {
            ((uint4*)Xb)[i] = ((const uint4*)x)[i];
        } else {
            const float* f = (const float*)x + (size_t)i * 8;
            unsigned short r[8];
            for (int j = 0; j < 8; ++j) r[j] = f2bfbits(f[j]);
            *(uint4*)(Xb + (size_t)i * 8) = *(uint4*)r;
        }
        return;
    }
    int u = i - 800000;
    const void* W; unsigned short* dst; int Nf, Npad, s, rem;
    if (u < 4096)        { W = W1; dst = W1f; Nf = 256; Npad = 256; s = u / 1024; rem = u % 1024; }
    else if (u < 12288)  { u -= 4096;  W = W2; dst = W2f; Nf = 256; Npad = 256; s = u / 1024; rem = u % 1024; }
    else if (u < 14336)  { u -= 12288; W = Wo; dst = Wof; Nf = 40;  Npad = 64;  s = u / 256;  rem = u % 256; }
    else return;
    int n = rem >> 2, quad = rem & 3;
    unsigned short r[8];
    for (int j = 0; j < 8; ++j) {
        int k = s * 32 + quad * 8 + j;
        r[j] = (n < Nf) ? f2bfbits(loadF(W, (size_t)k * Nf + n, bf)) : (unsigned short)0;
    }
    int uo = (s * Npad + n) * 4 + quad;
    *(uint4*)(dst + (size_t)uo * 8) = *(uint4*)r;
}

// ---------- CSR build ----------
__global__ void hist_k(const int* __restrict__ dst, int* __restrict__ cnt, int E) {
    int e = blockIdx.x * blockDim.x + threadIdx.x;
    if (e < E) atomicAdd(&cnt[dst[e]], 1);
}

__global__ void scan1_k(const int* __restrict__ deg, int* __restrict__ rowptr,
                        int* __restrict__ bsum, int N) {
    __shared__ int s[256];
    int t = threadIdx.x, g = blockIdx.x * 256 + t;
    int v = (g < N) ? deg[g] : 0;
    s[t] = v; __syncthreads();
    for (int off = 1; off < 256; off <<= 1) {
        int x = (t >= off) ? s[t - off] : 0;
        __syncthreads();
        s[t] += x;
        __syncthreads();
    }
    if (g < N) rowptr[g] = s[t] - v;
    if (t == 255) bsum[blockIdx.x] = s[255];
}

__global__ void scan23_k(int* __restrict__ rowptr, const int* __restrict__ bsum, int N, int E) {
    __shared__ int ws[4];
    __shared__ int s_off;
    int bid = blockIdx.x, t = threadIdx.x;
    int wave = t >> 6, lane = t & 63;
    int v = (t < bid) ? bsum[t] : 0;
    for (int off = 32; off; off >>= 1) v += __shfl_down(v, off, 64);
    if (lane == 0) ws[wave] = v;
    __syncthreads();
    if (t == 0) s_off = ws[0] + ws[1] + ws[2] + ws[3];
    __syncthreads();
    int g = bid * 256 + t;
    if (g < N) rowptr[g] += s_off;
    if (g == 0) rowptr[N] = E;
}

__global__ void scatter_k(const int* __restrict__ src, const int* __restrict__ dst,
                          const int* __restrict__ rowptr, int* __restrict__ cursor,
                          int* __restrict__ ecol, int E) {
    int e = blockIdx.x * blockDim.x + threadIdx.x;
    if (e >= E) return;
    int d = dst[e];
    int r = atomicSub(&cursor[d], 1);
    ecol[rowptr[d] + r - 1] = src[e];
}

// ---------- LDS-free MFMA GEMM + fused attention coefficients ----------
// AMODE 0: Nfull=256, C stride 256, direct el/er store per head.
// AMODE 1: output layer, C stride 64 incl. zero padding, atomicAdd el/er.
template <int K_, int AMODE>
__global__ __launch_bounds__(256)
void gemm_attn_k(const unsigned short* __restrict__ A, const unsigned short* __restrict__ Wf,
                 __hip_bfloat16* __restrict__ C, const void* __restrict__ al,
                 const void* __restrict__ ar, const int* __restrict__ flag,
                 float* __restrict__ el, float* __restrict__ er, int M, int Nfull, int Npad) {
    int t = threadIdx.x;
    int row0 = blockIdx.x * 128, col0 = blockIdx.y * 64;
    int wave = t >> 6, lane = t & 63;
    int wr = (wave >> 1) * 64, wc = (wave & 1) * 32;
    int m16 = lane & 15, quad = lane >> 4;

    const unsigned short* arow[4];
    for (int mt = 0; mt < 4; ++mt) {
        int gr = row0 + wr + mt * 16 + m16;
        int grc = (gr < M) ? gr : (M - 1);
        arow[mt] = A + (size_t)grc * K_ + quad * 8;
    }
    const unsigned short* bbase[2];
    for (int nt = 0; nt < 2; ++nt) {
        int gc = col0 + wc + nt * 16 + m16;
        bbase[nt] = Wf + ((size_t)(gc * 4 + quad) << 3);
    }

    f32x4 acc[4][2] = {};
#pragma unroll
    for (int s = 0; s < K_ / 32; ++s) {
        bf16x8 a[4], b[2];
        for (int mt = 0; mt < 4; ++mt)
            a[mt] = *(const bf16x8*)(arow[mt] + s * 32);
        for (int nt = 0; nt < 2; ++nt)
            b[nt] = *(const bf16x8*)(bbase[nt] + (size_t)s * Npad * 32);
        for (int mt = 0; mt < 4; ++mt)
            for (int nt = 0; nt < 2; ++nt)
                acc[mt][nt] = __builtin_amdgcn_mfma_f32_16x16x32_bf16(
                    a[mt], b[nt], acc[mt][nt], 0, 0, 0);
    }

    // C store (D layout: row = quad*4+r, col = m16)
    int cld = (AMODE == 0) ? Nfull : Npad;
    for (int mt = 0; mt < 4; ++mt)
        for (int nt = 0; nt < 2; ++nt)
            for (int r = 0; r < 4; ++r) {
                int gr = row0 + wr + mt * 16 + quad * 4 + r;
                int gc = col0 + wc + nt * 16 + m16;
                if (gr < M && gc < cld)
                    C[(size_t)gr * cld + gc] = __float2bfloat16(acc[mt][nt][r]);
            }

    // fused attention coefficients
    bool bf = (*flag != 0);
    float alc[2], arc[2];
    for (int nt = 0; nt < 2; ++nt) {
        int gc = col0 + wc + nt * 16 + m16;
        bool ok = gc < Nfull;
        alc[nt] = ok ? loadF(al, gc, bf) : 0.f;
        arc[nt] = ok ? loadF(ar, gc, bf) : 0.f;
    }
    for (int mt = 0; mt < 4; ++mt)
        for (int r = 0; r < 4; ++r) {
            float pl = acc[mt][0][r] * alc[0] + acc[mt][1][r] * alc[1];
            float pr = acc[mt][0][r] * arc[0] + acc[mt][1][r] * arc[1];
            for (int off = 1; off < 16; off <<= 1) {
                pl += __shfl_xor(pl, off, 64);
                pr += __shfl_xor(pr, off, 64);
            }
            if (m16 == 0) {
                int gr = row0 + wr + mt * 16 + quad * 4 + r;
                if (gr < M) {
                    if (AMODE == 0) {
                        int hd = col0 / 32 + (wave & 1);
                        el[gr * 8 + hd] = pl;
                        er[gr * 8 + hd] = pr;
                    } else {
                        atomicAdd(&el[gr], pl);
                        atomicAdd(&er[gr], pr);
                    }
                }
            }
        }
}

// ---------- single-pass half-wave aggregation (H=8, F=32), unrolled x4 ----------
__global__ __launch_bounds__(256)
void aggr1_k(const int* __restrict__ rowptr, const int* __restrict__ ecol,
             const float* __restrict__ el, const float* __restrict__ er,
             const __hip_bfloat16* __restrict__ Hp, __hip_bfloat16* __restrict__ out, int N) {
    int t = threadIdx.x;
    int hw = t >> 5, l = t & 31;
    int n = blockIdx.x * 8 + hw;
    if (n >= N) return;
    int beg = rowptr[n], deg = rowptr[n + 1] - beg;

    int hh = l >> 2;
    float er_hh = er[n * 8 + hh];
    float ss = 0.f;
    float acc[8] = {0.f, 0.f, 0.f, 0.f, 0.f, 0.f, 0.f, 0.f};
    const unsigned short* hp = (const unsigned short*)Hp;

    int i = 0;
    for (; i + 4 <= deg; i += 4) {
        int s0 = ecol[beg + i], s1 = ecol[beg + i + 1];
        int s2 = ecol[beg + i + 2], s3 = ecol[beg + i + 3];
        uint4 r0 = *(const uint4*)(hp + (size_t)s0 * 256 + l * 8);
        uint4 r1 = *(const uint4*)(hp + (size_t)s1 * 256 + l * 8);
        uint4 r2 = *(const uint4*)(hp + (size_t)s2 * 256 + l * 8);
        uint4 r3 = *(const uint4*)(hp + (size_t)s3 * 256 + l * 8);
        float v0 = el[s0 * 8 + hh] + er_hh;
        float v1 = el[s1 * 8 + hh] + er_hh;
        float v2 = el[s2 * 8 + hh] + er_hh;
        float v3 = el[s3 * 8 + hh] + er_hh;
        v0 = (v0 >= 0.f) ? v0 : 0.2f * v0;
        v1 = (v1 >= 0.f) ? v1 : 0.2f * v1;
        v2 = (v2 >= 0.f) ? v2 : 0.2f * v2;
        v3 = (v3 >= 0.f) ? v3 : 0.2f * v3;
        float e0 = __expf(v0), e1 = __expf(v1), e2 = __expf(v2), e3 = __expf(v3);
        ss += (e0 + e1) + (e2 + e3);
        unsigned short u0[8], u1[8], u2[8], u3[8];
        *(uint4*)u0 = r0;
        *(uint4*)u1 = r1;
        *(uint4*)u2 = r2;
        *(uint4*)u3 = r3;
        for (int j = 0; j < 8; ++j)
            acc[j] += (e0 * bfbits2f(u0[j]) + e1 * bfbits2f(u1[j])) +
                      (e2 * bfbits2f(u2[j]) + e3 * bfbits2f(u3[j]));
    }
    for (; i < deg; ++i) {
        int s0 = ecol[beg + i];
        uint4 r0 = *(const uint4*)(hp + (size_t)s0 * 256 + l * 8);
        float v0 = el[s0 * 8 + hh] + er_hh;
        v0 = (v0 >= 0.f) ? v0 : 0.2f * v0;
        float e0 = __expf(v0);
        ss += e0;
        unsigned short u0[8];
        *(uint4*)u0 = r0;
        for (int j = 0; j < 8; ++j) acc[j] += e0 * bfbits2f(u0[j]);
    }

    float inv = 1.f / (ss + 1e-16f);
    unsigned short o[8];
    for (int j = 0; j < 8; ++j) {
        float vv = acc[j] * inv;
        vv = (vv > 0.f) ? vv : expm1f(vv);   // ELU
        o[j] = f2bfbits(vv);
    }
    *(uint4*)((unsigned short*)out + (size_t)n * 256 + l * 8) = *(uint4*)o;
}

// ---------- output layer: 8-way vectorized aggregation (stride-64 Hp) + log_softmax ----------
// lane l: g = l>>3 (edge group), f = l&7 (feature slot [8f,8f+8), f<5 useful).
__global__ __launch_bounds__(64)
void aggr_out_k(const int* __restrict__ rowptr, const int* __restrict__ ecol,
                const float* __restrict__ elo, const float* __restrict__ ero,
                const unsigned short* __restrict__ Hp64, void* __restrict__ outp,
                const int* __restrict__ flag, int N) {
    int n = blockIdx.x, l = threadIdx.x;
    int g = l >> 3, f = l & 7;
    int beg = rowptr[n], deg = rowptr[n + 1] - beg;
    float ero_n = ero[n];
    float ss = 0.f;
    float acc[8] = {0.f, 0.f, 0.f, 0.f, 0.f, 0.f, 0.f, 0.f};
    for (int i = g; i < deg; i += 8) {
        int s = ecol[beg + i];
        float v = elo[s] + ero_n;
        v = (v >= 0.f) ? v : 0.2f * v;
        float ex = __expf(v);
        ss += ex;
        uint4 r = *(const uint4*)(Hp64 + (size_t)s * 64 + f * 8);
        unsigned short u[8];
        *(uint4*)u = r;
        for (int j = 0; j < 8; ++j) acc[j] += ex * bfbits2f(u[j]);
    }
    // reduce across the 8 edge groups (xor bits 3..5)
    for (int off = 8; off <= 32; off <<= 1) {
        ss += __shfl_xor(ss, off, 64);
        for (int j = 0; j < 8; ++j) acc[j] += __shfl_xor(acc[j], off, 64);
    }
    float inv = 1.f / (ss + 1e-16f);
    float r8[8];
    float vmax = -1e30f;
    for (int j = 0; j < 8; ++j) {
        r8[j] = acc[j] * inv;
        if (f < 5) vmax = fmaxf(vmax, r8[j]);
    }
    // log_softmax across the 40 classes (xor bits 0..2 over feature slots)
    for (int off = 1; off <= 4; off <<= 1) vmax = fmaxf(vmax, __shfl_xor(vmax, off, 64));
    float es = 0.f;
    if (f < 5)
        for (int j = 0; j < 8; ++j) es += __expf(r8[j] - vmax);
    for (int off = 1; off <= 4; off <<= 1) es += __shfl_xor(es, off, 64);
    float lse = vmax + logf(es);
    if (f < 5 && g == 0) {
        if (*flag) {
            unsigned short o[8];
            for (int j = 0; j < 8; ++j) o[j] = f2bfbits(r8[j] - lse);
            *(uint4*)((unsigned short*)outp + (size_t)n * 40 + f * 8) = *(uint4*)o;
        } else {
            float* fo = (float*)outp + (size_t)n * 40 + f * 8;
            for (int j = 0; j < 8; ++j) fo[j] = r8[j] - lse;
        }
    }
}

extern "C" void kernel_launch(void* const* d_in, const int* in_sizes, int n_in,
                              void* d_out, int out_size, void* d_ws, size_t ws_size,
                              hipStream_t stream) {
    const int N = N_NODES, E = N_EDGES;
    const void* x   = d_in[0];
    const int* src  = (const int*)d_in[1];
    const int* dst  = (const int*)d_in[2];
    const void* W1  = d_in[3];
    const void* al1 = d_in[4];
    const void* ar1 = d_in[5];
    const void* W2  = d_in[6];
    const void* al2 = d_in[7];
    const void* ar2 = d_in[8];
    const void* Wo  = d_in[9];
    const void* alo = d_in[10];
    const void* aro = d_in[11];

    // workspace (~58.6 MB)
    char* w = (char*)d_ws;
    auto alloc = [&](size_t bytes) { void* p = (void*)w; w += (bytes + 255) & ~(size_t)255; return p; };
    int* flag      = (int*)alloc(4);
    int* rowptr    = (int*)alloc((size_t)(N + 1) * 4);
    int* cursor    = (int*)alloc((size_t)N * 4);
    float* elo     = (float*)alloc((size_t)N * 4);
    float* ero     = (float*)alloc((size_t)N * 4);
    int* bsum      = (int*)alloc(256 * 4);
    int* ecol      = (int*)alloc((size_t)E * 4);
    float* el      = (float*)alloc((size_t)N * 8 * 4);
    float* er      = (float*)alloc((size_t)N * 8 * 4);
    unsigned short* W1f = (unsigned short*)alloc((size_t)128 * 256 * 2);
    unsigned short* W2f = (unsigned short*)alloc((size_t)256 * 256 * 2);
    unsigned short* Wof = (unsigned short*)alloc((size_t)256 * 64 * 2);
    __hip_bfloat16* Hp   = (__hip_bfloat16*)alloc((size_t)N * 256 * 2);
    __hip_bfloat16* Hagg = (__hip_bfloat16*)alloc((size_t)N * 256 * 2);
    unsigned short* Xb = (unsigned short*)Hagg;   // alias: dead after layer-1 gemm

    int EB = (E + 255) / 256;
    int NB = (N + 255) / 256;
    int MB = (N + 127) / 128;
    int AB = (N + 7) / 8;

    detect_k<<<1, 64, 0, stream>>>((const unsigned short*)x, flag);
    cvt_all_k<<<(814336 + 255) / 256, 256, 0, stream>>>(x, W1, W2, Wo, Xb, W1f, W2f, Wof, flag);
    hipMemsetAsync(cursor, 0, (size_t)N * 3 * 4, stream);  // cursor + elo + ero
    hist_k<<<EB, 256, 0, stream>>>(dst, cursor, E);
    scan1_k<<<NB, 256, 0, stream>>>(cursor, rowptr, bsum, N);
    scan23_k<<<NB, 256, 0, stream>>>(rowptr, bsum, N, E);
    scatter_k<<<EB, 256, 0, stream>>>(src, dst, rowptr, cursor, ecol, E);

    // layer 1
    gemm_attn_k<128, 0><<<dim3(MB, 4), 256, 0, stream>>>(Xb, W1f, Hp, al1, ar1, flag, el, er, N, 256, 256);
    aggr1_k<<<AB, 256, 0, stream>>>(rowptr, ecol, el, er, Hp, Hagg, N);

    // layer 2
    gemm_attn_k<256, 0><<<dim3(MB, 4), 256, 0, stream>>>((const unsigned short*)Hagg, W2f, Hp, al2, ar2, flag, el, er, N, 256, 256);
    aggr1_k<<<AB, 256, 0, stream>>>(rowptr, ecol, el, er, Hp, Hagg, N);

    // output layer (C stored with stride 64, zero-padded cols 40..63)
    gemm_attn_k<256, 1><<<dim3(MB, 1), 256, 0, stream>>>((const unsigned short*)Hagg, Wof, Hp, alo, aro, flag, elo, ero, N, 40, 64);
    aggr_out_k<<<N, 64, 0, stream>>>(rowptr, ecol, elo, ero, (const unsigned short*)Hp, d_out, flag, N);
}